// Round 1
// baseline (860.285 us; speedup 1.0000x reference)
//
#include <hip/hip_runtime.h>

#define NU_   40000
#define NI_   60000
#define NTOT  100000
#define D_    128
#define NNZ_  1600000
#define B_    4096

// ---------------------------------------------------------------- init X0 = concat(user_emb, item_emb)
__global__ void init_x0(const float* __restrict__ ue, const float* __restrict__ ie,
                        float* __restrict__ X0) {
    const int total = NTOT * 32;              // float4 count = N*128/4
    const int ucnt  = NU_ * 32;
    for (int i = blockIdx.x * blockDim.x + threadIdx.x; i < total; i += gridDim.x * blockDim.x) {
        float4 v = (i < ucnt) ? ((const float4*)ue)[i] : ((const float4*)ie)[i - ucnt];
        ((float4*)X0)[i] = v;
    }
}

// ---------------------------------------------------------------- CSR build
__global__ void hist_kernel(const int* __restrict__ row, int* __restrict__ cnt, int nnz) {
    int i = blockIdx.x * blockDim.x + threadIdx.x;
    if (i < nnz) atomicAdd(&cnt[row[i]], 1);
}

__global__ void scan_blk(const int* __restrict__ cnt, int* __restrict__ blk, int n) {
    __shared__ int s[256];
    int t = threadIdx.x;
    int base = blockIdx.x * 1024 + t * 4;
    int tot = 0;
#pragma unroll
    for (int i = 0; i < 4; ++i) { int idx = base + i; if (idx < n) tot += cnt[idx]; }
    s[t] = tot; __syncthreads();
    for (int off = 128; off; off >>= 1) { if (t < off) s[t] += s[t + off]; __syncthreads(); }
    if (t == 0) blk[blockIdx.x] = s[0];
}

__global__ void scan_mid(int* __restrict__ blk, int nb, int* __restrict__ rowp, int n, int nnz) {
    if (threadIdx.x == 0 && blockIdx.x == 0) {
        int run = 0;
        for (int i = 0; i < nb; ++i) { int v = blk[i]; blk[i] = run; run += v; }
        rowp[n] = nnz;
    }
}

__global__ void scan_fin(const int* __restrict__ cnt, const int* __restrict__ blk,
                         int* __restrict__ rowp, int n) {
    __shared__ int s[256];
    int t = threadIdx.x;
    int base = blockIdx.x * 1024 + t * 4;
    int v[4]; int tot = 0;
#pragma unroll
    for (int i = 0; i < 4; ++i) { v[i] = (base + i < n) ? cnt[base + i] : 0; tot += v[i]; }
    s[t] = tot; __syncthreads();
    for (int off = 1; off < 256; off <<= 1) {
        int x = (t >= off) ? s[t - off] : 0; __syncthreads();
        s[t] += x; __syncthreads();
    }
    int run = s[t] - tot + blk[blockIdx.x];
#pragma unroll
    for (int i = 0; i < 4; ++i) { if (base + i < n) rowp[base + i] = run; run += v[i]; }
}

__global__ void scatter_kernel(const int* __restrict__ row, const int* __restrict__ colin,
                               const float* __restrict__ valin, int* __restrict__ cursor,
                               int* __restrict__ ccol, float* __restrict__ cval, int nnz) {
    int e = blockIdx.x * blockDim.x + threadIdx.x;
    if (e < nnz) {
        int r = row[e];
        int p = atomicAdd(&cursor[r], 1);
        ccol[p] = colin[e];
        cval[p] = valin[e];
    }
}

// ---------------------------------------------------------------- full SpMM: y = A x  (wave per row, float2 per lane)
__global__ __launch_bounds__(256) void spmm_csr(const int* __restrict__ rowp,
                                                const int* __restrict__ ccol,
                                                const float* __restrict__ cval,
                                                const float* __restrict__ x,
                                                float* __restrict__ y) {
    int r = blockIdx.x * 4 + (threadIdx.x >> 6);
    int lane = threadIdx.x & 63;
    if (r >= NTOT) return;
    const float2* x2 = (const float2*)x;
    int s = rowp[r], e = rowp[r + 1];
    float2 acc = make_float2(0.f, 0.f);
    for (int i = s; i < e; ++i) {
        int c = ccol[i];
        float v = cval[i];
        float2 xv = x2[c * 64 + lane];
        acc.x += v * xv.x;
        acc.y += v * xv.y;
    }
    ((float2*)y)[r * 64 + lane] = acc;
}

// ---------------------------------------------------------------- gather x_layer[sel] into Xb cols 0:256
__global__ void gather_rows(const float* __restrict__ x, const int* __restrict__ uids,
                            const int* __restrict__ iids, float* __restrict__ Xb, int add) {
    int g = blockIdx.x;         // 0..2B-1
    int t = threadIdx.x;        // 0..127
    int batch, cb, row;
    if (g < B_) { batch = g;      cb = 0;   row = uids[g]; }
    else        { batch = g - B_; cb = 128; row = NU_ + iids[g - B_]; }
    float v = x[row * 128 + t];
    float* p = &Xb[batch * 1024 + cb + t];
    if (add) *p += v; else *p = v;
}

// ---------------------------------------------------------------- partial layer-3 SpMM on selected rows, + x2[sel], *0.25
__global__ __launch_bounds__(256) void spmm_sel(const int* __restrict__ rowp,
                                                const int* __restrict__ ccol,
                                                const float* __restrict__ cval,
                                                const float* __restrict__ x2in,
                                                const int* __restrict__ uids,
                                                const int* __restrict__ iids,
                                                float* __restrict__ Xb) {
    int g = blockIdx.x * 4 + (threadIdx.x >> 6);
    int lane = threadIdx.x & 63;
    if (g >= 2 * B_) return;
    int batch, cb, row;
    if (g < B_) { batch = g;      cb = 0;   row = uids[g]; }
    else        { batch = g - B_; cb = 128; row = NU_ + iids[g - B_]; }
    const float2* x2 = (const float2*)x2in;
    float2 acc = x2[row * 64 + lane];            // x2 own-row contribution
    int s = rowp[row], e = rowp[row + 1];
    for (int i = s; i < e; ++i) {
        int c = ccol[i];
        float v = cval[i];
        float2 xv = x2[c * 64 + lane];
        acc.x += v * xv.x;
        acc.y += v * xv.y;
    }
    float2* p = (float2*)(Xb + batch * 1024 + cb) + lane;
    float2 cur = *p;
    cur.x = (cur.x + acc.x) * 0.25f;
    cur.y = (cur.y + acc.y) * 0.25f;
    *p = cur;
}

// ---------------------------------------------------------------- small feature GEMM: [B,K]@[K,128] -> Xb[:, colbase:colbase+128]
template <int K>
__global__ void feat_gemm(const float* __restrict__ A, const float* __restrict__ W,
                          float* __restrict__ Xb, int colbase) {
    __shared__ float Ws[K * 128];
    int t = threadIdx.x;        // 0..127
    for (int i = t; i < K * 128; i += 128) Ws[i] = W[i];
    __syncthreads();
    int row0 = blockIdx.x * 8;
    for (int r = 0; r < 8; ++r) {
        int row = row0 + r;
        const float* a = A + row * K;
        float acc = 0.f;
#pragma unroll
        for (int k = 0; k < K; ++k) acc += a[k] * Ws[k * 128 + t];
        Xb[row * 1024 + colbase + t] = acc;
    }
}

// ---------------------------------------------------------------- fp32 tiled GEMM: C[M,N] = act(A[M,K]@W[K,N] + b)
__global__ __launch_bounds__(256) void fc_gemm(const float* __restrict__ A,
                                               const float* __restrict__ W,
                                               const float* __restrict__ bias,
                                               float* __restrict__ C,
                                               int M, int N, int K, int doRelu) {
    __shared__ float As[16][68];
    __shared__ float Bs[16][68];
    int m0 = blockIdx.y * 64, n0 = blockIdx.x * 64;
    int t = threadIdx.x;
    int tx = t & 15, ty = t >> 4;
    float acc[4][4] = {};
    for (int k0 = 0; k0 < K; k0 += 16) {
#pragma unroll
        for (int i = 0; i < 4; ++i) {
            int idx = t + i * 256;          // 0..1023
            int m = idx >> 4, k = idx & 15;
            As[k][m] = A[(m0 + m) * K + k0 + k];
        }
#pragma unroll
        for (int i = 0; i < 4; ++i) {
            int idx = t + i * 256;
            int k = idx >> 6, n = idx & 63;
            Bs[k][n] = W[(k0 + k) * N + n0 + n];
        }
        __syncthreads();
#pragma unroll
        for (int k = 0; k < 16; ++k) {
            float4 a = *(const float4*)&As[k][ty * 4];
            float4 b = *(const float4*)&Bs[k][tx * 4];
            acc[0][0] += a.x * b.x; acc[0][1] += a.x * b.y; acc[0][2] += a.x * b.z; acc[0][3] += a.x * b.w;
            acc[1][0] += a.y * b.x; acc[1][1] += a.y * b.y; acc[1][2] += a.y * b.z; acc[1][3] += a.y * b.w;
            acc[2][0] += a.z * b.x; acc[2][1] += a.z * b.y; acc[2][2] += a.z * b.z; acc[2][3] += a.z * b.w;
            acc[3][0] += a.w * b.x; acc[3][1] += a.w * b.y; acc[3][2] += a.w * b.z; acc[3][3] += a.w * b.w;
        }
        __syncthreads();
    }
#pragma unroll
    for (int i = 0; i < 4; ++i) {
        int m = m0 + ty * 4 + i;
#pragma unroll
        for (int j = 0; j < 4; ++j) {
            int n = n0 + tx * 4 + j;
            float v = acc[i][j] + bias[n];
            if (doRelu) v = fmaxf(v, 0.f);
            C[m * N + n] = v;
        }
    }
}

// ---------------------------------------------------------------- out layer: [B,256]@[256,1] + b
__global__ void out_layer(const float* __restrict__ H2, const float* __restrict__ W,
                          const float* __restrict__ b, float* __restrict__ out) {
    int row = blockIdx.x;
    int lane = threadIdx.x;     // 64
    float4 h = ((const float4*)(H2 + row * 256))[lane];
    float4 w = ((const float4*)W)[lane];
    float acc = h.x * w.x + h.y * w.y + h.z * w.z + h.w * w.w;
    for (int off = 32; off; off >>= 1) acc += __shfl_down(acc, off, 64);
    if (lane == 0) out[row] = acc + b[0];
}

// ================================================================ launch
extern "C" void kernel_launch(void* const* d_in, const int* in_sizes, int n_in,
                              void* d_out, int out_size, void* d_ws, size_t ws_size,
                              hipStream_t stream) {
    const float* user_feat0 = (const float*)d_in[0];
    const float* user_feat1 = (const float*)d_in[1];
    const float* user_feat2 = (const float*)d_in[2];
    const float* item_feat0 = (const float*)d_in[3];
    const float* item_feat1 = (const float*)d_in[4];
    const float* item_feat2 = (const float*)d_in[5];
    const int*   user_ids   = (const int*)d_in[6];
    const int*   item_ids   = (const int*)d_in[7];
    const int*   adj_row    = (const int*)d_in[8];
    const int*   adj_col    = (const int*)d_in[9];
    const float* adj_val    = (const float*)d_in[10];
    const float* user_emb   = (const float*)d_in[11];
    const float* item_emb   = (const float*)d_in[12];
    const float* Wu0 = (const float*)d_in[13];
    const float* Wu1 = (const float*)d_in[14];
    const float* Wu2 = (const float*)d_in[15];
    const float* Wi0 = (const float*)d_in[16];
    const float* Wi1 = (const float*)d_in[17];
    const float* Wi2 = (const float*)d_in[18];
    const float* fc1_W = (const float*)d_in[19];
    const float* fc1_b = (const float*)d_in[20];
    const float* fc2_W = (const float*)d_in[21];
    const float* fc2_b = (const float*)d_in[22];
    const float* out_W = (const float*)d_in[23];
    const float* out_b = (const float*)d_in[24];
    float* out = (float*)d_out;

    // workspace carve-up (256B aligned)
    size_t off = 0;
    auto alloc = [&](size_t bytes) { size_t o = off; off += (bytes + 255) & ~(size_t)255; return o; };
    char* ws = (char*)d_ws;
    float* X0   = (float*)(ws + alloc((size_t)NTOT * 128 * 4));
    float* X1   = (float*)(ws + alloc((size_t)NTOT * 128 * 4));
    int*   rowp = (int*)  (ws + alloc((size_t)(NTOT + 1) * 4));
    int*   cnt  = (int*)  (ws + alloc((size_t)NTOT * 4));        // also reused as scatter cursor
    int*   blk  = (int*)  (ws + alloc(128 * 4));
    int*   ccol = (int*)  (ws + alloc((size_t)NNZ_ * 4));
    float* cval = (float*)(ws + alloc((size_t)NNZ_ * 4));
    float* Xb   = (float*)(ws + alloc((size_t)B_ * 1024 * 4));
    float* H1   = (float*)(ws + alloc((size_t)B_ * 512 * 4));
    float* H2   = (float*)(ws + alloc((size_t)B_ * 256 * 4));

    const int NB = (NTOT + 1023) / 1024;   // 98

    // 1) X0 = concat(embs); counts = 0
    init_x0<<<2048, 256, 0, stream>>>(user_emb, item_emb, X0);
    hipMemsetAsync(cnt, 0, (size_t)NTOT * 4, stream);

    // 2) CSR build
    hist_kernel<<<(NNZ_ + 255) / 256, 256, 0, stream>>>(adj_row, cnt, NNZ_);
    scan_blk<<<NB, 256, 0, stream>>>(cnt, blk, NTOT);
    scan_mid<<<1, 64, 0, stream>>>(blk, NB, rowp, NTOT, NNZ_);
    scan_fin<<<NB, 256, 0, stream>>>(cnt, blk, rowp, NTOT);
    hipMemcpyAsync(cnt, rowp, (size_t)NTOT * 4, hipMemcpyDeviceToDevice, stream);  // cursor
    scatter_kernel<<<(NNZ_ + 255) / 256, 256, 0, stream>>>(adj_row, adj_col, adj_val, cnt, ccol, cval, NNZ_);

    // 3) propagation: acc(selected) = x0 + x1 + x2 + x3, /4
    gather_rows<<<2 * B_, 128, 0, stream>>>(X0, user_ids, item_ids, Xb, /*add=*/0);
    spmm_csr<<<(NTOT + 3) / 4, 256, 0, stream>>>(rowp, ccol, cval, X0, X1);       // x1
    gather_rows<<<2 * B_, 128, 0, stream>>>(X1, user_ids, item_ids, Xb, /*add=*/1);
    spmm_csr<<<(NTOT + 3) / 4, 256, 0, stream>>>(rowp, ccol, cval, X1, X0);       // x2 (into X0 buf)
    spmm_sel<<<(2 * B_ + 3) / 4, 256, 0, stream>>>(rowp, ccol, cval, X0, user_ids, item_ids, Xb);

    // 4) feature MLP columns
    feat_gemm<64><<<B_ / 8, 128, 0, stream>>>(user_feat0, Wu0, Xb, 256);
    feat_gemm<32><<<B_ / 8, 128, 0, stream>>>(user_feat1, Wu1, Xb, 384);
    feat_gemm<16><<<B_ / 8, 128, 0, stream>>>(user_feat2, Wu2, Xb, 512);
    feat_gemm<64><<<B_ / 8, 128, 0, stream>>>(item_feat0, Wi0, Xb, 640);
    feat_gemm<32><<<B_ / 8, 128, 0, stream>>>(item_feat1, Wi1, Xb, 768);
    feat_gemm<16><<<B_ / 8, 128, 0, stream>>>(item_feat2, Wi2, Xb, 896);

    // 5) MLP tail
    fc_gemm<<<dim3(512 / 64, B_ / 64), 256, 0, stream>>>(Xb, fc1_W, fc1_b, H1, B_, 512, 1024, 1);
    fc_gemm<<<dim3(256 / 64, B_ / 64), 256, 0, stream>>>(H1, fc2_W, fc2_b, H2, B_, 256, 512, 1);
    out_layer<<<B_, 64, 0, stream>>>(H2, out_W, out_b, out);
}

// Round 2
// 684.746 us; speedup vs baseline: 1.2564x; 1.2564x over previous
//
#include <hip/hip_runtime.h>

#define NU_   40000
#define NI_   60000
#define NTOT  100000
#define D_    128
#define NNZ_  1600000
#define B_    4096

typedef unsigned int uint_t;

// ---- bf16 pack/unpack (2 dims per uint, little-endian: lo=dim0, hi=dim1) ----
__device__ __forceinline__ uint_t pack_bf16(float lo, float hi) {
    uint_t ul = __float_as_uint(lo);
    uint_t uh = __float_as_uint(hi);
    ul = (ul + 0x7fffu + ((ul >> 16) & 1u)) >> 16;
    uh = (uh + 0x7fffu + ((uh >> 16) & 1u)) >> 16;
    return ul | (uh << 16);
}
__device__ __forceinline__ float2 unpack_bf16(uint_t u) {
    return make_float2(__uint_as_float(u << 16), __uint_as_float(u & 0xffff0000u));
}

// ---------------------------------------------------------------- X0 (bf16) = concat(user_emb, item_emb)
__global__ void cvt_x0(const float* __restrict__ ue, const float* __restrict__ ie,
                       uint_t* __restrict__ x0b) {
    const int total = NTOT * 64;              // uint count = N*128/2
    const int ucnt  = NU_ * 64;
    for (int i = blockIdx.x * blockDim.x + threadIdx.x; i < total; i += gridDim.x * blockDim.x) {
        float2 v = (i < ucnt) ? ((const float2*)ue)[i] : ((const float2*)ie)[i - ucnt];
        x0b[i] = pack_bf16(v.x, v.y);
    }
}

// ---------------------------------------------------------------- CSR build
__global__ void hist_kernel(const int* __restrict__ row, int* __restrict__ cnt, int nnz) {
    int i = blockIdx.x * blockDim.x + threadIdx.x;
    if (i < nnz) atomicAdd(&cnt[row[i]], 1);
}

__global__ void scan_blk(const int* __restrict__ cnt, int* __restrict__ blk, int n) {
    __shared__ int s[256];
    int t = threadIdx.x;
    int base = blockIdx.x * 1024 + t * 4;
    int tot = 0;
#pragma unroll
    for (int i = 0; i < 4; ++i) { int idx = base + i; if (idx < n) tot += cnt[idx]; }
    s[t] = tot; __syncthreads();
    for (int off = 128; off; off >>= 1) { if (t < off) s[t] += s[t + off]; __syncthreads(); }
    if (t == 0) blk[blockIdx.x] = s[0];
}

__global__ void scan_mid(int* __restrict__ blk, int nb, int* __restrict__ rowp, int n, int nnz) {
    if (threadIdx.x == 0 && blockIdx.x == 0) {
        int run = 0;
        for (int i = 0; i < nb; ++i) { int v = blk[i]; blk[i] = run; run += v; }
        rowp[n] = nnz;
    }
}

__global__ void scan_fin(const int* __restrict__ cnt, const int* __restrict__ blk,
                         int* __restrict__ rowp, int n) {
    __shared__ int s[256];
    int t = threadIdx.x;
    int base = blockIdx.x * 1024 + t * 4;
    int v[4]; int tot = 0;
#pragma unroll
    for (int i = 0; i < 4; ++i) { v[i] = (base + i < n) ? cnt[base + i] : 0; tot += v[i]; }
    s[t] = tot; __syncthreads();
    for (int off = 1; off < 256; off <<= 1) {
        int x = (t >= off) ? s[t - off] : 0; __syncthreads();
        s[t] += x; __syncthreads();
    }
    int run = s[t] - tot + blk[blockIdx.x];
#pragma unroll
    for (int i = 0; i < 4; ++i) { if (base + i < n) rowp[base + i] = run; run += v[i]; }
}

// scatter edges into CSR order as int2{col, val_bits}
__global__ void scatter_kernel(const int* __restrict__ row, const int* __restrict__ colin,
                               const float* __restrict__ valin, int* __restrict__ cursor,
                               int2* __restrict__ cedge, int nnz) {
    int e = blockIdx.x * blockDim.x + threadIdx.x;
    if (e < nnz) {
        int r = row[e];
        int p = atomicAdd(&cursor[r], 1);
        cedge[p] = make_int2(colin[e], __float_as_int(valin[e]));
    }
}

// ---------------------------------------------------------------- full SpMM (bf16 in/out, fp32 acc)
// wave per row; manual unroll-8: 8 edge loads -> 8 independent gathers -> 8 FMAs
__global__ __launch_bounds__(256) void spmm_bf16(const int* __restrict__ rowp,
                                                 const int2* __restrict__ cedge,
                                                 const uint_t* __restrict__ xb,
                                                 uint_t* __restrict__ yb) {
    int r = blockIdx.x * 4 + (threadIdx.x >> 6);
    int lane = threadIdx.x & 63;
    if (r >= NTOT) return;
    int s = rowp[r], e = rowp[r + 1];
    float ax = 0.f, ay = 0.f;
    for (int i = s; i < e; i += 8) {
        int2 ed[8];
#pragma unroll
        for (int t = 0; t < 8; ++t) {
            int idx = i + t;
            ed[t] = cedge[idx < e ? idx : i];
            if (idx >= e) ed[t].y = 0;            // value := 0.0f for tail
        }
        uint_t g[8];
#pragma unroll
        for (int t = 0; t < 8; ++t) g[t] = xb[(size_t)(uint_t)ed[t].x * 64 + lane];
#pragma unroll
        for (int t = 0; t < 8; ++t) {
            float v = __int_as_float(ed[t].y);
            float2 xv = unpack_bf16(g[t]);
            ax = fmaf(v, xv.x, ax);
            ay = fmaf(v, xv.y, ay);
        }
    }
    yb[(size_t)r * 64 + lane] = pack_bf16(ax, ay);
}

// ---------------------------------------------------------------- Xb[:,0:256] = x0[sel] + x1[sel]
__global__ __launch_bounds__(256) void gather2(const uint_t* __restrict__ x0b,
                                               const uint_t* __restrict__ x1b,
                                               const int* __restrict__ uids,
                                               const int* __restrict__ iids,
                                               float* __restrict__ Xb) {
    int g = blockIdx.x * 4 + (threadIdx.x >> 6);
    int lane = threadIdx.x & 63;
    if (g >= 2 * B_) return;
    int batch, cb, row;
    if (g < B_) { batch = g;      cb = 0;   row = uids[g]; }
    else        { batch = g - B_; cb = 128; row = NU_ + iids[g - B_]; }
    float2 a = unpack_bf16(x0b[(size_t)row * 64 + lane]);
    float2 b = unpack_bf16(x1b[(size_t)row * 64 + lane]);
    ((float2*)(Xb + batch * 1024 + cb))[lane] = make_float2(a.x + b.x, a.y + b.y);
}

// ---------------------------------------------------------------- layer-3 partial SpMM on selected rows
__global__ __launch_bounds__(256) void spmm_sel(const int* __restrict__ rowp,
                                                const int2* __restrict__ cedge,
                                                const uint_t* __restrict__ x2b,
                                                const int* __restrict__ uids,
                                                const int* __restrict__ iids,
                                                float* __restrict__ Xb) {
    int g = blockIdx.x * 4 + (threadIdx.x >> 6);
    int lane = threadIdx.x & 63;
    if (g >= 2 * B_) return;
    int batch, cb, row;
    if (g < B_) { batch = g;      cb = 0;   row = uids[g]; }
    else        { batch = g - B_; cb = 128; row = NU_ + iids[g - B_]; }
    float2 own = unpack_bf16(x2b[(size_t)row * 64 + lane]);   // x2 own-row term
    float ax = own.x, ay = own.y;
    int s = rowp[row], e = rowp[row + 1];
    for (int i = s; i < e; i += 8) {
        int2 ed[8];
#pragma unroll
        for (int t = 0; t < 8; ++t) {
            int idx = i + t;
            ed[t] = cedge[idx < e ? idx : i];
            if (idx >= e) ed[t].y = 0;
        }
        uint_t gv[8];
#pragma unroll
        for (int t = 0; t < 8; ++t) gv[t] = x2b[(size_t)(uint_t)ed[t].x * 64 + lane];
#pragma unroll
        for (int t = 0; t < 8; ++t) {
            float v = __int_as_float(ed[t].y);
            float2 xv = unpack_bf16(gv[t]);
            ax = fmaf(v, xv.x, ax);
            ay = fmaf(v, xv.y, ay);
        }
    }
    float2* p = (float2*)(Xb + batch * 1024 + cb) + lane;
    float2 cur = *p;
    cur.x = (cur.x + ax) * 0.25f;
    cur.y = (cur.y + ay) * 0.25f;
    *p = cur;
}

// ---------------------------------------------------------------- small feature GEMM: [B,K]@[K,128] -> Xb[:, colbase:+128]
template <int K>
__global__ void feat_gemm(const float* __restrict__ A, const float* __restrict__ W,
                          float* __restrict__ Xb, int colbase) {
    __shared__ float Ws[K * 128];
    int t = threadIdx.x;        // 0..127
    for (int i = t; i < K * 128; i += 128) Ws[i] = W[i];
    __syncthreads();
    int row0 = blockIdx.x * 8;
    for (int r = 0; r < 8; ++r) {
        int row = row0 + r;
        const float* a = A + row * K;
        float acc = 0.f;
#pragma unroll
        for (int k = 0; k < K; ++k) acc += a[k] * Ws[k * 128 + t];
        Xb[row * 1024 + colbase + t] = acc;
    }
}

// ---------------------------------------------------------------- fp32 tiled GEMM: C[M,N] = act(A[M,K]@W[K,N] + b)
__global__ __launch_bounds__(256) void fc_gemm(const float* __restrict__ A,
                                               const float* __restrict__ W,
                                               const float* __restrict__ bias,
                                               float* __restrict__ C,
                                               int M, int N, int K, int doRelu) {
    __shared__ float As[16][68];
    __shared__ float Bs[16][68];
    int m0 = blockIdx.y * 64, n0 = blockIdx.x * 64;
    int t = threadIdx.x;
    int tx = t & 15, ty = t >> 4;
    float acc[4][4] = {};
    for (int k0 = 0; k0 < K; k0 += 16) {
#pragma unroll
        for (int i = 0; i < 4; ++i) {
            int idx = t + i * 256;          // 0..1023
            int m = idx >> 4, k = idx & 15;
            As[k][m] = A[(m0 + m) * K + k0 + k];
        }
#pragma unroll
        for (int i = 0; i < 4; ++i) {
            int idx = t + i * 256;
            int k = idx >> 6, n = idx & 63;
            Bs[k][n] = W[(k0 + k) * N + n0 + n];
        }
        __syncthreads();
#pragma unroll
        for (int k = 0; k < 16; ++k) {
            float4 a = *(const float4*)&As[k][ty * 4];
            float4 b = *(const float4*)&Bs[k][tx * 4];
            acc[0][0] += a.x * b.x; acc[0][1] += a.x * b.y; acc[0][2] += a.x * b.z; acc[0][3] += a.x * b.w;
            acc[1][0] += a.y * b.x; acc[1][1] += a.y * b.y; acc[1][2] += a.y * b.z; acc[1][3] += a.y * b.w;
            acc[2][0] += a.z * b.x; acc[2][1] += a.z * b.y; acc[2][2] += a.z * b.z; acc[2][3] += a.z * b.w;
            acc[3][0] += a.w * b.x; acc[3][1] += a.w * b.y; acc[3][2] += a.w * b.z; acc[3][3] += a.w * b.w;
        }
        __syncthreads();
    }
#pragma unroll
    for (int i = 0; i < 4; ++i) {
        int m = m0 + ty * 4 + i;
#pragma unroll
        for (int j = 0; j < 4; ++j) {
            int n = n0 + tx * 4 + j;
            float v = acc[i][j] + bias[n];
            if (doRelu) v = fmaxf(v, 0.f);
            C[m * N + n] = v;
        }
    }
}

// ---------------------------------------------------------------- out layer: [B,256]@[256,1] + b
__global__ void out_layer(const float* __restrict__ H2, const float* __restrict__ W,
                          const float* __restrict__ b, float* __restrict__ out) {
    int row = blockIdx.x;
    int lane = threadIdx.x;     // 64
    float4 h = ((const float4*)(H2 + row * 256))[lane];
    float4 w = ((const float4*)W)[lane];
    float acc = h.x * w.x + h.y * w.y + h.z * w.z + h.w * w.w;
    for (int off = 32; off; off >>= 1) acc += __shfl_down(acc, off, 64);
    if (lane == 0) out[row] = acc + b[0];
}

// ================================================================ launch
extern "C" void kernel_launch(void* const* d_in, const int* in_sizes, int n_in,
                              void* d_out, int out_size, void* d_ws, size_t ws_size,
                              hipStream_t stream) {
    const float* user_feat0 = (const float*)d_in[0];
    const float* user_feat1 = (const float*)d_in[1];
    const float* user_feat2 = (const float*)d_in[2];
    const float* item_feat0 = (const float*)d_in[3];
    const float* item_feat1 = (const float*)d_in[4];
    const float* item_feat2 = (const float*)d_in[5];
    const int*   user_ids   = (const int*)d_in[6];
    const int*   item_ids   = (const int*)d_in[7];
    const int*   adj_row    = (const int*)d_in[8];
    const int*   adj_col    = (const int*)d_in[9];
    const float* adj_val    = (const float*)d_in[10];
    const float* user_emb   = (const float*)d_in[11];
    const float* item_emb   = (const float*)d_in[12];
    const float* Wu0 = (const float*)d_in[13];
    const float* Wu1 = (const float*)d_in[14];
    const float* Wu2 = (const float*)d_in[15];
    const float* Wi0 = (const float*)d_in[16];
    const float* Wi1 = (const float*)d_in[17];
    const float* Wi2 = (const float*)d_in[18];
    const float* fc1_W = (const float*)d_in[19];
    const float* fc1_b = (const float*)d_in[20];
    const float* fc2_W = (const float*)d_in[21];
    const float* fc2_b = (const float*)d_in[22];
    const float* out_W = (const float*)d_in[23];
    const float* out_b = (const float*)d_in[24];
    float* out = (float*)d_out;

    // workspace carve-up (256B aligned)
    size_t off = 0;
    auto alloc = [&](size_t bytes) { size_t o = off; off += (bytes + 255) & ~(size_t)255; return o; };
    char* ws = (char*)d_ws;
    uint_t* x0b  = (uint_t*)(ws + alloc((size_t)NTOT * 64 * 4));
    uint_t* x1b  = (uint_t*)(ws + alloc((size_t)NTOT * 64 * 4));
    uint_t* x2b  = (uint_t*)(ws + alloc((size_t)NTOT * 64 * 4));
    int*   rowp  = (int*)  (ws + alloc((size_t)(NTOT + 1) * 4));
    int*   cnt   = (int*)  (ws + alloc((size_t)NTOT * 4));        // also reused as scatter cursor
    int*   blk   = (int*)  (ws + alloc(128 * 4));
    int2*  cedge = (int2*) (ws + alloc((size_t)NNZ_ * 8));
    float* Xb    = (float*)(ws + alloc((size_t)B_ * 1024 * 4));
    float* H1    = (float*)(ws + alloc((size_t)B_ * 512 * 4));
    float* H2    = (float*)(ws + alloc((size_t)B_ * 256 * 4));

    const int NB = (NTOT + 1023) / 1024;   // 98

    // 1) X0 = bf16(concat(embs)); counts = 0
    cvt_x0<<<2048, 256, 0, stream>>>(user_emb, item_emb, x0b);
    hipMemsetAsync(cnt, 0, (size_t)NTOT * 4, stream);

    // 2) CSR build
    hist_kernel<<<(NNZ_ + 255) / 256, 256, 0, stream>>>(adj_row, cnt, NNZ_);
    scan_blk<<<NB, 256, 0, stream>>>(cnt, blk, NTOT);
    scan_mid<<<1, 64, 0, stream>>>(blk, NB, rowp, NTOT, NNZ_);
    scan_fin<<<NB, 256, 0, stream>>>(cnt, blk, rowp, NTOT);
    hipMemcpyAsync(cnt, rowp, (size_t)NTOT * 4, hipMemcpyDeviceToDevice, stream);  // cursor
    scatter_kernel<<<(NNZ_ + 255) / 256, 256, 0, stream>>>(adj_row, adj_col, adj_val, cnt, cedge, NNZ_);

    // 3) propagation: Xb(sel) = (x0 + x1 + x2 + x3)/4
    spmm_bf16<<<(NTOT + 3) / 4, 256, 0, stream>>>(rowp, cedge, x0b, x1b);          // x1
    gather2<<<(2 * B_ + 3) / 4, 256, 0, stream>>>(x0b, x1b, user_ids, item_ids, Xb);
    spmm_bf16<<<(NTOT + 3) / 4, 256, 0, stream>>>(rowp, cedge, x1b, x2b);          // x2
    spmm_sel<<<(2 * B_ + 3) / 4, 256, 0, stream>>>(rowp, cedge, x2b, user_ids, item_ids, Xb);

    // 4) feature MLP columns
    feat_gemm<64><<<B_ / 8, 128, 0, stream>>>(user_feat0, Wu0, Xb, 256);
    feat_gemm<32><<<B_ / 8, 128, 0, stream>>>(user_feat1, Wu1, Xb, 384);
    feat_gemm<16><<<B_ / 8, 128, 0, stream>>>(user_feat2, Wu2, Xb, 512);
    feat_gemm<64><<<B_ / 8, 128, 0, stream>>>(item_feat0, Wi0, Xb, 640);
    feat_gemm<32><<<B_ / 8, 128, 0, stream>>>(item_feat1, Wi1, Xb, 768);
    feat_gemm<16><<<B_ / 8, 128, 0, stream>>>(item_feat2, Wi2, Xb, 896);

    // 5) MLP tail
    fc_gemm<<<dim3(512 / 64, B_ / 64), 256, 0, stream>>>(Xb, fc1_W, fc1_b, H1, B_, 512, 1024, 1);
    fc_gemm<<<dim3(256 / 64, B_ / 64), 256, 0, stream>>>(H1, fc2_W, fc2_b, H2, B_, 256, 512, 1);
    out_layer<<<B_, 64, 0, stream>>>(H2, out_W, out_b, out);
}

// Round 7
// 586.254 us; speedup vs baseline: 1.4674x; 1.1680x over previous
//
#include <hip/hip_runtime.h>

#define NU_   40000
#define NI_   60000
#define NTOT  100000
#define D_    128
#define NNZ_  1600000
#define B_    4096

#define BSH   7
#define NBKT  ((NTOT + 127) >> 7)            // 782 buckets of 128 rows
#define CHUNK 16384
#define NCH   ((NNZ_ + CHUNK - 1) / CHUNK)   // 98
#define BCAP  2560                            // bucket capacity (mean 2048 + 11 sigma)

typedef unsigned int uint_t;

// ---- bf16 pack/unpack (2 dims per uint, lo=dim0, hi=dim1) ----
__device__ __forceinline__ uint_t pack_bf16(float lo, float hi) {
    uint_t ul = __float_as_uint(lo);
    uint_t uh = __float_as_uint(hi);
    ul = (ul + 0x7fffu + ((ul >> 16) & 1u)) >> 16;
    uh = (uh + 0x7fffu + ((uh >> 16) & 1u)) >> 16;
    return ul | (uh << 16);
}
__device__ __forceinline__ float2 unpack_bf16(uint_t u) {
    return make_float2(__uint_as_float(u << 16), __uint_as_float(u & 0xffff0000u));
}

// ---------------------------------------------------------------- X0 (bf16) = concat(user_emb, item_emb)
__global__ void cvt_x0(const float* __restrict__ ue, const float* __restrict__ ie,
                       uint_t* __restrict__ x0b) {
    const int total = NTOT * 64;
    const int ucnt  = NU_ * 64;
    for (int i = blockIdx.x * blockDim.x + threadIdx.x; i < total; i += gridDim.x * blockDim.x) {
        float2 v = (i < ucnt) ? ((const float2*)ue)[i] : ((const float2*)ie)[i - ucnt];
        x0b[i] = pack_bf16(v.x, v.y);
    }
}

// ---------------------------------------------------------------- bucket histogram (LDS-staged)
__global__ __launch_bounds__(256) void bucket_hist(const int* __restrict__ row,
                                                   int* __restrict__ gcnt) {
    __shared__ int lcnt[NBKT];
    for (int i = threadIdx.x; i < NBKT; i += 256) lcnt[i] = 0;
    __syncthreads();
    for (int i = blockIdx.x * blockDim.x + threadIdx.x; i < NNZ_; i += gridDim.x * blockDim.x)
        atomicAdd(&lcnt[row[i] >> BSH], 1);
    __syncthreads();
    for (int i = threadIdx.x; i < NBKT; i += 256)
        if (lcnt[i]) atomicAdd(&gcnt[i], lcnt[i]);
}

// ---------------------------------------------------------------- bucket offsets (single block scan over 782)
__global__ __launch_bounds__(256) void bucket_scan(const int* __restrict__ gcnt,
                                                   int* __restrict__ base,
                                                   int* __restrict__ cursor,
                                                   int* __restrict__ rowp) {
    __shared__ int s[256];
    int t = threadIdx.x;
    int b0 = t * 4;
    int v[4]; int tot = 0;
#pragma unroll
    for (int i = 0; i < 4; ++i) { v[i] = (b0 + i < NBKT) ? gcnt[b0 + i] : 0; tot += v[i]; }
    s[t] = tot; __syncthreads();
    for (int off = 1; off < 256; off <<= 1) {
        int x = (t >= off) ? s[t - off] : 0; __syncthreads();
        s[t] += x; __syncthreads();
    }
    int run = s[t] - tot;
#pragma unroll
    for (int i = 0; i < 4; ++i) {
        if (b0 + i < NBKT) { base[b0 + i] = run; cursor[b0 + i] = run; }
        run += v[i];
    }
    if (t == 0) rowp[NTOT] = NNZ_;
}

// ---------------------------------------------------------------- partition: chunked count-reserve-scatter
// writes per (chunk,bucket) are contiguous runs (~160B) -> low write amplification
__global__ __launch_bounds__(256) void partition_edges(const int* __restrict__ row,
                                                       const int* __restrict__ col,
                                                       const float* __restrict__ val,
                                                       int* __restrict__ cursor,
                                                       int2* __restrict__ pedge) {
    __shared__ int lcnt[NBKT];
    __shared__ int lbase[NBKT];
    int s = blockIdx.x * CHUNK;
    int e = min(s + CHUNK, NNZ_);
    for (int i = threadIdx.x; i < NBKT; i += 256) lcnt[i] = 0;
    __syncthreads();
    for (int i = s + threadIdx.x; i < e; i += 256)
        atomicAdd(&lcnt[row[i] >> BSH], 1);
    __syncthreads();
    for (int i = threadIdx.x; i < NBKT; i += 256) {
        int c = lcnt[i];
        lbase[i] = c ? atomicAdd(&cursor[i], c) : 0;
        lcnt[i] = 0;                 // reuse as running offset
    }
    __syncthreads();
    for (int i = s + threadIdx.x; i < e; i += 256) {
        int r = row[i];
        int b = r >> BSH;
        int pos = lbase[b] + atomicAdd(&lcnt[b], 1);
        // pack row-local (7b) above col (17b); val bits separate
        pedge[pos] = make_int2(((r & 127) << 17) | col[i], __float_as_int(val[i]));
    }
}

// ---------------------------------------------------------------- per-bucket LDS counting sort -> final CSR + rowp
__global__ __launch_bounds__(256) void bucket_sort(const int* __restrict__ gcnt,
                                                   const int* __restrict__ base,
                                                   const int2* __restrict__ pedge,
                                                   int2* __restrict__ cedge,
                                                   int* __restrict__ rowp) {
    __shared__ int rcnt[128];
    __shared__ int rstart[128];
    __shared__ int roff[128];
    __shared__ int2 sedge[BCAP];
    int b = blockIdx.x;
    int t = threadIdx.x;
    int n = gcnt[b];
    if (n > BCAP) n = BCAP;          // safety clamp (never expected)
    int gb = base[b];
    if (t < 128) { rcnt[t] = 0; roff[t] = 0; }
    __syncthreads();
    for (int i = t; i < n; i += 256) atomicAdd(&rcnt[pedge[gb + i].x >> 17], 1);
    __syncthreads();
    if (t < 128) rstart[t] = rcnt[t];
    __syncthreads();
    for (int off = 1; off < 128; off <<= 1) {
        int x = (t < 128 && t >= off) ? rstart[t - off] : 0;
        __syncthreads();
        if (t < 128) rstart[t] += x;
        __syncthreads();
    }
    int ex = (t < 128) ? (rstart[t] - rcnt[t]) : 0;
    __syncthreads();
    if (t < 128) rstart[t] = ex;
    __syncthreads();
    for (int i = t; i < n; i += 256) {
        int2 ed = pedge[gb + i];
        int rl = ed.x >> 17;
        int pos = rstart[rl] + atomicAdd(&roff[rl], 1);
        sedge[pos] = make_int2(ed.x & 0x1FFFF, ed.y);
    }
    __syncthreads();
    for (int i = t; i < n; i += 256) cedge[gb + i] = sedge[i];
    if (t < 128) {
        int r = (b << BSH) + t;
        if (r < NTOT) rowp[r] = gb + rstart[t];
    }
}

// ---------------------------------------------------------------- full SpMM (bf16 in/out, fp32 acc), unroll-8
__global__ __launch_bounds__(256) void spmm_bf16(const int* __restrict__ rowp,
                                                 const int2* __restrict__ cedge,
                                                 const uint_t* __restrict__ xb,
                                                 uint_t* __restrict__ yb) {
    int r = blockIdx.x * 4 + (threadIdx.x >> 6);
    int lane = threadIdx.x & 63;
    if (r >= NTOT) return;
    int s = rowp[r], e = rowp[r + 1];
    float ax = 0.f, ay = 0.f;
    for (int i = s; i < e; i += 8) {
        int2 ed[8];
#pragma unroll
        for (int t = 0; t < 8; ++t) {
            int idx = i + t;
            ed[t] = cedge[idx < e ? idx : i];
            if (idx >= e) ed[t].y = 0;
        }
        uint_t g[8];
#pragma unroll
        for (int t = 0; t < 8; ++t) g[t] = xb[(size_t)(uint_t)ed[t].x * 64 + lane];
#pragma unroll
        for (int t = 0; t < 8; ++t) {
            float v = __int_as_float(ed[t].y);
            float2 xv = unpack_bf16(g[t]);
            ax = fmaf(v, xv.x, ax);
            ay = fmaf(v, xv.y, ay);
        }
    }
    yb[(size_t)r * 64 + lane] = pack_bf16(ax, ay);
}

// ---------------------------------------------------------------- Xb[:,0:256] = x0[sel] + x1[sel]
__global__ __launch_bounds__(256) void gather2(const uint_t* __restrict__ x0b,
                                               const uint_t* __restrict__ x1b,
                                               const int* __restrict__ uids,
                                               const int* __restrict__ iids,
                                               float* __restrict__ Xb) {
    int g = blockIdx.x * 4 + (threadIdx.x >> 6);
    int lane = threadIdx.x & 63;
    if (g >= 2 * B_) return;
    int batch, cb, row;
    if (g < B_) { batch = g;      cb = 0;   row = uids[g]; }
    else        { batch = g - B_; cb = 128; row = NU_ + iids[g - B_]; }
    float2 a = unpack_bf16(x0b[(size_t)row * 64 + lane]);
    float2 b = unpack_bf16(x1b[(size_t)row * 64 + lane]);
    ((float2*)(Xb + batch * 1024 + cb))[lane] = make_float2(a.x + b.x, a.y + b.y);
}

// ---------------------------------------------------------------- layer-3 partial SpMM on selected rows
__global__ __launch_bounds__(256) void spmm_sel(const int* __restrict__ rowp,
                                                const int2* __restrict__ cedge,
                                                const uint_t* __restrict__ x2b,
                                                const int* __restrict__ uids,
                                                const int* __restrict__ iids,
                                                float* __restrict__ Xb) {
    int g = blockIdx.x * 4 + (threadIdx.x >> 6);
    int lane = threadIdx.x & 63;
    if (g >= 2 * B_) return;
    int batch, cb, row;
    if (g < B_) { batch = g;      cb = 0;   row = uids[g]; }
    else        { batch = g - B_; cb = 128; row = NU_ + iids[g - B_]; }
    float2 own = unpack_bf16(x2b[(size_t)row * 64 + lane]);
    float ax = own.x, ay = own.y;
    int s = rowp[row], e = rowp[row + 1];
    for (int i = s; i < e; i += 8) {
        int2 ed[8];
#pragma unroll
        for (int t = 0; t < 8; ++t) {
            int idx = i + t;
            ed[t] = cedge[idx < e ? idx : i];
            if (idx >= e) ed[t].y = 0;
        }
        uint_t gv[8];
#pragma unroll
        for (int t = 0; t < 8; ++t) gv[t] = x2b[(size_t)(uint_t)ed[t].x * 64 + lane];
#pragma unroll
        for (int t = 0; t < 8; ++t) {
            float v = __int_as_float(ed[t].y);
            float2 xv = unpack_bf16(gv[t]);
            ax = fmaf(v, xv.x, ax);
            ay = fmaf(v, xv.y, ay);
        }
    }
    float2* p = (float2*)(Xb + batch * 1024 + cb) + lane;
    float2 cur = *p;
    cur.x = (cur.x + ax) * 0.25f;
    cur.y = (cur.y + ay) * 0.25f;
    *p = cur;
}

// ---------------------------------------------------------------- small feature GEMM: [B,K]@[K,128] -> Xb[:, colbase:+128]
template <int K>
__global__ void feat_gemm(const float* __restrict__ A, const float* __restrict__ W,
                          float* __restrict__ Xb, int colbase) {
    __shared__ float Ws[K * 128];
    int t = threadIdx.x;
    for (int i = t; i < K * 128; i += 128) Ws[i] = W[i];
    __syncthreads();
    int row0 = blockIdx.x * 8;
    for (int r = 0; r < 8; ++r) {
        int row = row0 + r;
        const float* a = A + row * K;
        float acc = 0.f;
#pragma unroll
        for (int k = 0; k < K; ++k) acc += a[k] * Ws[k * 128 + t];
        Xb[row * 1024 + colbase + t] = acc;
    }
}

// ---------------------------------------------------------------- fp32 tiled GEMM: C[M,N] = act(A[M,K]@W[K,N] + b)
__global__ __launch_bounds__(256) void fc_gemm(const float* __restrict__ A,
                                               const float* __restrict__ W,
                                               const float* __restrict__ bias,
                                               float* __restrict__ C,
                                               int M, int N, int K, int doRelu) {
    __shared__ float As[16][68];
    __shared__ float Bs[16][68];
    int m0 = blockIdx.y * 64, n0 = blockIdx.x * 64;
    int t = threadIdx.x;
    int tx = t & 15, ty = t >> 4;
    float acc[4][4] = {};
    for (int k0 = 0; k0 < K; k0 += 16) {
#pragma unroll
        for (int i = 0; i < 4; ++i) {
            int idx = t + i * 256;
            int m = idx >> 4, k = idx & 15;
            As[k][m] = A[(m0 + m) * K + k0 + k];
        }
#pragma unroll
        for (int i = 0; i < 4; ++i) {
            int idx = t + i * 256;
            int k = idx >> 6, n = idx & 63;
            Bs[k][n] = W[(k0 + k) * N + n0 + n];
        }
        __syncthreads();
#pragma unroll
        for (int k = 0; k < 16; ++k) {
            float4 a = *(const float4*)&As[k][ty * 4];
            float4 b = *(const float4*)&Bs[k][tx * 4];
            acc[0][0] += a.x * b.x; acc[0][1] += a.x * b.y; acc[0][2] += a.x * b.z; acc[0][3] += a.x * b.w;
            acc[1][0] += a.y * b.x; acc[1][1] += a.y * b.y; acc[1][2] += a.y * b.z; acc[1][3] += a.y * b.w;
            acc[2][0] += a.z * b.x; acc[2][1] += a.z * b.y; acc[2][2] += a.z * b.z; acc[2][3] += a.z * b.w;
            acc[3][0] += a.w * b.x; acc[3][1] += a.w * b.y; acc[3][2] += a.w * b.z; acc[3][3] += a.w * b.w;
        }
        __syncthreads();
    }
#pragma unroll
    for (int i = 0; i < 4; ++i) {
        int m = m0 + ty * 4 + i;
#pragma unroll
        for (int j = 0; j < 4; ++j) {
            int n = n0 + tx * 4 + j;
            float v = acc[i][j] + bias[n];
            if (doRelu) v = fmaxf(v, 0.f);
            C[m * N + n] = v;
        }
    }
}

// ---------------------------------------------------------------- out layer: [B,256]@[256,1] + b
__global__ void out_layer(const float* __restrict__ H2, const float* __restrict__ W,
                          const float* __restrict__ b, float* __restrict__ out) {
    int row = blockIdx.x;
    int lane = threadIdx.x;
    float4 h = ((const float4*)(H2 + row * 256))[lane];
    float4 w = ((const float4*)W)[lane];
    float acc = h.x * w.x + h.y * w.y + h.z * w.z + h.w * w.w;
    for (int off = 32; off; off >>= 1) acc += __shfl_down(acc, off, 64);
    if (lane == 0) out[row] = acc + b[0];
}

// ================================================================ launch
extern "C" void kernel_launch(void* const* d_in, const int* in_sizes, int n_in,
                              void* d_out, int out_size, void* d_ws, size_t ws_size,
                              hipStream_t stream) {
    const float* user_feat0 = (const float*)d_in[0];
    const float* user_feat1 = (const float*)d_in[1];
    const float* user_feat2 = (const float*)d_in[2];
    const float* item_feat0 = (const float*)d_in[3];
    const float* item_feat1 = (const float*)d_in[4];
    const float* item_feat2 = (const float*)d_in[5];
    const int*   user_ids   = (const int*)d_in[6];
    const int*   item_ids   = (const int*)d_in[7];
    const int*   adj_row    = (const int*)d_in[8];
    const int*   adj_col    = (const int*)d_in[9];
    const float* adj_val    = (const float*)d_in[10];
    const float* user_emb   = (const float*)d_in[11];
    const float* item_emb   = (const float*)d_in[12];
    const float* Wu0 = (const float*)d_in[13];
    const float* Wu1 = (const float*)d_in[14];
    const float* Wu2 = (const float*)d_in[15];
    const float* Wi0 = (const float*)d_in[16];
    const float* Wi1 = (const float*)d_in[17];
    const float* Wi2 = (const float*)d_in[18];
    const float* fc1_W = (const float*)d_in[19];
    const float* fc1_b = (const float*)d_in[20];
    const float* fc2_W = (const float*)d_in[21];
    const float* fc2_b = (const float*)d_in[22];
    const float* out_W = (const float*)d_in[23];
    const float* out_b = (const float*)d_in[24];
    float* out = (float*)d_out;

    // workspace carve-up (256B aligned)
    size_t off = 0;
    auto alloc = [&](size_t bytes) { size_t o = off; off += (bytes + 255) & ~(size_t)255; return o; };
    char* ws = (char*)d_ws;
    uint_t* x0b   = (uint_t*)(ws + alloc((size_t)NTOT * 64 * 4));
    uint_t* x1b   = (uint_t*)(ws + alloc((size_t)NTOT * 64 * 4));
    int*    rowp  = (int*)  (ws + alloc((size_t)(NTOT + 1) * 4));
    int*    gcnt  = (int*)  (ws + alloc((size_t)NBKT * 4));
    int*    bbase = (int*)  (ws + alloc((size_t)NBKT * 4));
    int*    bcur  = (int*)  (ws + alloc((size_t)NBKT * 4));
    int2*   pedge = (int2*) (ws + alloc((size_t)NNZ_ * 8));
    int2*   cedge = (int2*) (ws + alloc((size_t)NNZ_ * 8));
    float*  Xb    = (float*)(ws + alloc((size_t)B_ * 1024 * 4));
    float*  H1    = (float*)(ws + alloc((size_t)B_ * 512 * 4));
    float*  H2    = (float*)(ws + alloc((size_t)B_ * 256 * 4));

    // 1) X0 = bf16(concat(embs)); bucket counters = 0
    cvt_x0<<<2048, 256, 0, stream>>>(user_emb, item_emb, x0b);
    hipMemsetAsync(gcnt, 0, (size_t)NBKT * 4, stream);

    // 2) CSR build via bucketed counting sort
    bucket_hist<<<256, 256, 0, stream>>>(adj_row, gcnt);
    bucket_scan<<<1, 256, 0, stream>>>(gcnt, bbase, bcur, rowp);
    partition_edges<<<NCH, 256, 0, stream>>>(adj_row, adj_col, adj_val, bcur, pedge);
    bucket_sort<<<NBKT, 256, 0, stream>>>(gcnt, bbase, pedge, cedge, rowp);

    // 3) propagation: Xb(sel) = (x0 + x1 + x2 + x3)/4
    spmm_bf16<<<(NTOT + 3) / 4, 256, 0, stream>>>(rowp, cedge, x0b, x1b);          // x1
    gather2<<<(2 * B_ + 3) / 4, 256, 0, stream>>>(x0b, x1b, user_ids, item_ids, Xb);
    spmm_bf16<<<(NTOT + 3) / 4, 256, 0, stream>>>(rowp, cedge, x1b, x0b);          // x2 (reuse x0b)
    spmm_sel<<<(2 * B_ + 3) / 4, 256, 0, stream>>>(rowp, cedge, x0b, user_ids, item_ids, Xb);

    // 4) feature MLP columns
    feat_gemm<64><<<B_ / 8, 128, 0, stream>>>(user_feat0, Wu0, Xb, 256);
    feat_gemm<32><<<B_ / 8, 128, 0, stream>>>(user_feat1, Wu1, Xb, 384);
    feat_gemm<16><<<B_ / 8, 128, 0, stream>>>(user_feat2, Wu2, Xb, 512);
    feat_gemm<64><<<B_ / 8, 128, 0, stream>>>(item_feat0, Wi0, Xb, 640);
    feat_gemm<32><<<B_ / 8, 128, 0, stream>>>(item_feat1, Wi1, Xb, 768);
    feat_gemm<16><<<B_ / 8, 128, 0, stream>>>(item_feat2, Wi2, Xb, 896);

    // 5) MLP tail
    fc_gemm<<<dim3(512 / 64, B_ / 64), 256, 0, stream>>>(Xb, fc1_W, fc1_b, H1, B_, 512, 1024, 1);
    fc_gemm<<<dim3(256 / 64, B_ / 64), 256, 0, stream>>>(H1, fc2_W, fc2_b, H2, B_, 256, 512, 1);
    out_layer<<<B_, 64, 0, stream>>>(H2, out_W, out_b, out);
}

// Round 10
// 503.826 us; speedup vs baseline: 1.7075x; 1.1636x over previous
//
#include <hip/hip_runtime.h>

#define NU_   40000
#define NI_   60000
#define NTOT  100000
#define D_    128
#define NNZ_  1600000
#define B_    4096

#define BSH   7
#define NBKT  ((NTOT + 127) >> 7)            // 782 buckets of 128 rows
#define CHUNK 16384
#define NCH   ((NNZ_ + CHUNK - 1) / CHUNK)   // 98
#define BCAP  2560                            // bucket capacity (mean 2048 + 11 sigma)

typedef unsigned int uint_t;
typedef unsigned short ushort_t;
typedef __attribute__((ext_vector_type(8))) short short8v;
typedef __attribute__((ext_vector_type(4))) float float4v;

// ---- bf16 pack/unpack ----
__device__ __forceinline__ uint_t pack_bf16(float lo, float hi) {
    uint_t ul = __float_as_uint(lo);
    uint_t uh = __float_as_uint(hi);
    ul = (ul + 0x7fffu + ((ul >> 16) & 1u)) >> 16;
    uh = (uh + 0x7fffu + ((uh >> 16) & 1u)) >> 16;
    return ul | (uh << 16);
}
__device__ __forceinline__ float2 unpack_bf16(uint_t u) {
    return make_float2(__uint_as_float(u << 16), __uint_as_float(u & 0xffff0000u));
}
__device__ __forceinline__ ushort_t bf16r(float f) {
    uint_t u = __float_as_uint(f);
    return (ushort_t)((u + 0x7fffu + ((u >> 16) & 1u)) >> 16);
}

// ---------------------------------------------------------------- X0 (bf16) = concat(user_emb, item_emb)
__global__ void cvt_x0(const float* __restrict__ ue, const float* __restrict__ ie,
                       uint_t* __restrict__ x0b) {
    const int total = NTOT * 64;
    const int ucnt  = NU_ * 64;
    for (int i = blockIdx.x * blockDim.x + threadIdx.x; i < total; i += gridDim.x * blockDim.x) {
        float2 v = (i < ucnt) ? ((const float2*)ue)[i] : ((const float2*)ie)[i - ucnt];
        x0b[i] = pack_bf16(v.x, v.y);
    }
}

// ---------------------------------------------------------------- W [K][N] f32 -> Wt [N][K] bf16
__global__ void cvt_wt(const float* __restrict__ W, ushort_t* __restrict__ Wt, int K, int N) {
    int idx = blockIdx.x * blockDim.x + threadIdx.x;
    if (idx < K * N) {
        int k = idx / N, n = idx % N;
        Wt[(size_t)n * K + k] = bf16r(W[idx]);
    }
}

// ---------------------------------------------------------------- bucket histogram (LDS-staged)
__global__ __launch_bounds__(256) void bucket_hist(const int* __restrict__ row,
                                                   int* __restrict__ gcnt) {
    __shared__ int lcnt[NBKT];
    for (int i = threadIdx.x; i < NBKT; i += 256) lcnt[i] = 0;
    __syncthreads();
    for (int i = blockIdx.x * blockDim.x + threadIdx.x; i < NNZ_; i += gridDim.x * blockDim.x)
        atomicAdd(&lcnt[row[i] >> BSH], 1);
    __syncthreads();
    for (int i = threadIdx.x; i < NBKT; i += 256)
        if (lcnt[i]) atomicAdd(&gcnt[i], lcnt[i]);
}

// ---------------------------------------------------------------- bucket offsets (single block scan over 782)
__global__ __launch_bounds__(256) void bucket_scan(const int* __restrict__ gcnt,
                                                   int* __restrict__ base,
                                                   int* __restrict__ cursor,
                                                   int* __restrict__ rowp) {
    __shared__ int s[256];
    int t = threadIdx.x;
    int b0 = t * 4;
    int v[4]; int tot = 0;
#pragma unroll
    for (int i = 0; i < 4; ++i) { v[i] = (b0 + i < NBKT) ? gcnt[b0 + i] : 0; tot += v[i]; }
    s[t] = tot; __syncthreads();
    for (int off = 1; off < 256; off <<= 1) {
        int x = (t >= off) ? s[t - off] : 0; __syncthreads();
        s[t] += x; __syncthreads();
    }
    int run = s[t] - tot;
#pragma unroll
    for (int i = 0; i < 4; ++i) {
        if (b0 + i < NBKT) { base[b0 + i] = run; cursor[b0 + i] = run; }
        run += v[i];
    }
    if (t == 0) rowp[NTOT] = NNZ_;
}

// ---------------------------------------------------------------- partition: chunked count-reserve-scatter
__global__ __launch_bounds__(256) void partition_edges(const int* __restrict__ row,
                                                       const int* __restrict__ col,
                                                       const float* __restrict__ val,
                                                       int* __restrict__ cursor,
                                                       int2* __restrict__ pedge) {
    __shared__ int lcnt[NBKT];
    __shared__ int lbase[NBKT];
    int s = blockIdx.x * CHUNK;
    int e = min(s + CHUNK, NNZ_);
    for (int i = threadIdx.x; i < NBKT; i += 256) lcnt[i] = 0;
    __syncthreads();
    for (int i = s + threadIdx.x; i < e; i += 256)
        atomicAdd(&lcnt[row[i] >> BSH], 1);
    __syncthreads();
    for (int i = threadIdx.x; i < NBKT; i += 256) {
        int c = lcnt[i];
        lbase[i] = c ? atomicAdd(&cursor[i], c) : 0;
        lcnt[i] = 0;                 // reuse as running offset
    }
    __syncthreads();
    for (int i = s + threadIdx.x; i < e; i += 256) {
        int r = row[i];
        int b = r >> BSH;
        int pos = lbase[b] + atomicAdd(&lcnt[b], 1);
        pedge[pos] = make_int2(((r & 127) << 17) | col[i], __float_as_int(val[i]));
    }
}

// ---------------------------------------------------------------- per-bucket LDS counting sort -> final CSR + rowp
__global__ __launch_bounds__(256) void bucket_sort(const int* __restrict__ gcnt,
                                                   const int* __restrict__ base,
                                                   const int2* __restrict__ pedge,
                                                   int2* __restrict__ cedge,
                                                   int* __restrict__ rowp) {
    __shared__ int rcnt[128];
    __shared__ int rstart[128];
    __shared__ int roff[128];
    __shared__ int2 sedge[BCAP];
    int b = blockIdx.x;
    int t = threadIdx.x;
    int n = gcnt[b];
    if (n > BCAP) n = BCAP;
    int gb = base[b];
    if (t < 128) { rcnt[t] = 0; roff[t] = 0; }
    __syncthreads();
    for (int i = t; i < n; i += 256) atomicAdd(&rcnt[pedge[gb + i].x >> 17], 1);
    __syncthreads();
    if (t < 128) rstart[t] = rcnt[t];
    __syncthreads();
    for (int off = 1; off < 128; off <<= 1) {
        int x = (t < 128 && t >= off) ? rstart[t - off] : 0;
        __syncthreads();
        if (t < 128) rstart[t] += x;
        __syncthreads();
    }
    int ex = (t < 128) ? (rstart[t] - rcnt[t]) : 0;
    __syncthreads();
    if (t < 128) rstart[t] = ex;
    __syncthreads();
    for (int i = t; i < n; i += 256) {
        int2 ed = pedge[gb + i];
        int rl = ed.x >> 17;
        int pos = rstart[rl] + atomicAdd(&roff[rl], 1);
        sedge[pos] = make_int2(ed.x & 0x1FFFF, ed.y);
    }
    __syncthreads();
    for (int i = t; i < n; i += 256) cedge[gb + i] = sedge[i];
    if (t < 128) {
        int r = (b << BSH) + t;
        if (r < NTOT) rowp[r] = gb + rstart[t];
    }
}

// ---------------------------------------------------------------- full SpMM (bf16 in/out, fp32 acc), unroll-8
__global__ __launch_bounds__(256) void spmm_bf16(const int* __restrict__ rowp,
                                                 const int2* __restrict__ cedge,
                                                 const uint_t* __restrict__ xb,
                                                 uint_t* __restrict__ yb) {
    int r = blockIdx.x * 4 + (threadIdx.x >> 6);
    int lane = threadIdx.x & 63;
    if (r >= NTOT) return;
    int s = rowp[r], e = rowp[r + 1];
    float ax = 0.f, ay = 0.f;
    for (int i = s; i < e; i += 8) {
        int2 ed[8];
#pragma unroll
        for (int t = 0; t < 8; ++t) {
            int idx = i + t;
            ed[t] = cedge[idx < e ? idx : i];
            if (idx >= e) ed[t].y = 0;
        }
        uint_t g[8];
#pragma unroll
        for (int t = 0; t < 8; ++t) g[t] = xb[(size_t)(uint_t)ed[t].x * 64 + lane];
#pragma unroll
        for (int t = 0; t < 8; ++t) {
            float v = __int_as_float(ed[t].y);
            float2 xv = unpack_bf16(g[t]);
            ax = fmaf(v, xv.x, ax);
            ay = fmaf(v, xv.y, ay);
        }
    }
    yb[(size_t)r * 64 + lane] = pack_bf16(ax, ay);
}

// ---------------------------------------------------------------- Xh[:,0:256] (bf16) = x0[sel] + x1[sel]
__global__ __launch_bounds__(256) void gather2(const uint_t* __restrict__ x0b,
                                               const uint_t* __restrict__ x1b,
                                               const int* __restrict__ uids,
                                               const int* __restrict__ iids,
                                               uint_t* __restrict__ Xhu) {
    int g = blockIdx.x * 4 + (threadIdx.x >> 6);
    int lane = threadIdx.x & 63;
    if (g >= 2 * B_) return;
    int batch, seg, row;
    if (g < B_) { batch = g;      seg = 0; row = uids[g]; }
    else        { batch = g - B_; seg = 1; row = NU_ + iids[g - B_]; }
    float2 a = unpack_bf16(x0b[(size_t)row * 64 + lane]);
    float2 b = unpack_bf16(x1b[(size_t)row * 64 + lane]);
    Xhu[batch * 512 + seg * 64 + lane] = pack_bf16(a.x + b.x, a.y + b.y);
}

// ---------------------------------------------------------------- layer-3 partial SpMM on selected rows (bf16 out)
__global__ __launch_bounds__(256) void spmm_sel(const int* __restrict__ rowp,
                                                const int2* __restrict__ cedge,
                                                const uint_t* __restrict__ x2b,
                                                const int* __restrict__ uids,
                                                const int* __restrict__ iids,
                                                uint_t* __restrict__ Xhu) {
    int g = blockIdx.x * 4 + (threadIdx.x >> 6);
    int lane = threadIdx.x & 63;
    if (g >= 2 * B_) return;
    int batch, seg, row;
    if (g < B_) { batch = g;      seg = 0; row = uids[g]; }
    else        { batch = g - B_; seg = 1; row = NU_ + iids[g - B_]; }
    float2 own = unpack_bf16(x2b[(size_t)row * 64 + lane]);
    float ax = own.x, ay = own.y;
    int s = rowp[row], e = rowp[row + 1];
    for (int i = s; i < e; i += 8) {
        int2 ed[8];
#pragma unroll
        for (int t = 0; t < 8; ++t) {
            int idx = i + t;
            ed[t] = cedge[idx < e ? idx : i];
            if (idx >= e) ed[t].y = 0;
        }
        uint_t gv[8];
#pragma unroll
        for (int t = 0; t < 8; ++t) gv[t] = x2b[(size_t)(uint_t)ed[t].x * 64 + lane];
#pragma unroll
        for (int t = 0; t < 8; ++t) {
            float v = __int_as_float(ed[t].y);
            float2 xv = unpack_bf16(gv[t]);
            ax = fmaf(v, xv.x, ax);
            ay = fmaf(v, xv.y, ay);
        }
    }
    uint_t* p = Xhu + batch * 512 + seg * 64 + lane;
    float2 cur = unpack_bf16(*p);
    *p = pack_bf16((cur.x + ax) * 0.25f, (cur.y + ay) * 0.25f);
}

// ---------------------------------------------------------------- small feature GEMM: [B,K]@[K,128] -> Xh[:, colbase:+128] bf16
template <int K>
__global__ void feat_gemm(const float* __restrict__ A, const float* __restrict__ W,
                          ushort_t* __restrict__ Xh, int colbase) {
    __shared__ float Ws[K * 128];
    int t = threadIdx.x;
    for (int i = t; i < K * 128; i += 128) Ws[i] = W[i];
    __syncthreads();
    int row0 = blockIdx.x * 8;
    for (int r = 0; r < 8; ++r) {
        int row = row0 + r;
        const float* a = A + row * K;
        float acc = 0.f;
#pragma unroll
        for (int k = 0; k < K; ++k) acc += a[k] * Ws[k * 128 + t];
        Xh[row * 1024 + colbase + t] = bf16r(acc);
    }
}

// ---------------------------------------------------------------- bf16 MFMA GEMM: C[M,N] = act(A[M,K] @ Bt[N,K]^T + bias)
// 64x64 tile, 4 waves (2x2 of 32x32), 16x16x32 mfma, XOR-swizzled LDS.
template <int OUT_BF16>
__global__ __launch_bounds__(256) void mfma_fc(const ushort_t* __restrict__ A,   // [M][K] bf16
                                               const ushort_t* __restrict__ Bt,  // [N][K] bf16
                                               const float* __restrict__ bias,
                                               void* __restrict__ C,
                                               int M, int N, int K, int doRelu) {
    __shared__ __align__(16) ushort_t As[64 * 64];
    __shared__ __align__(16) ushort_t Bs[64 * 64];
    int t = threadIdx.x;
    int lane = t & 63, wid = t >> 6;
    int wr = wid >> 1, wc = wid & 1;
    int l15 = lane & 15, lhi = lane >> 4;
    int m0 = blockIdx.y * 64, n0 = blockIdx.x * 64;
    float4v acc[2][2] = {};
    for (int k0 = 0; k0 < K; k0 += 64) {
#pragma unroll
        for (int it = 0; it < 2; ++it) {
            int idx = t + it * 256;          // 0..511
            int r = idx >> 3, g = idx & 7;
            int gs = g ^ (r & 7);
            *(uint4*)&As[r * 64 + gs * 8] = *(const uint4*)&A[(size_t)(m0 + r) * K + k0 + g * 8];
            *(uint4*)&Bs[r * 64 + gs * 8] = *(const uint4*)&Bt[(size_t)(n0 + r) * K + k0 + g * 8];
        }
        __syncthreads();
#pragma unroll
        for (int ks = 0; ks < 2; ++ks) {
            short8v a[2], b[2];
            int g = 4 * ks + lhi;
#pragma unroll
            for (int m = 0; m < 2; ++m) {
                int ra = 32 * wr + 16 * m + l15;
                a[m] = *(short8v*)&As[ra * 64 + (g ^ (ra & 7)) * 8];
            }
#pragma unroll
            for (int n = 0; n < 2; ++n) {
                int rb = 32 * wc + 16 * n + l15;
                b[n] = *(short8v*)&Bs[rb * 64 + (g ^ (rb & 7)) * 8];
            }
#pragma unroll
            for (int m = 0; m < 2; ++m)
#pragma unroll
                for (int n = 0; n < 2; ++n)
                    acc[m][n] = __builtin_amdgcn_mfma_f32_16x16x32_bf16(a[m], b[n], acc[m][n], 0, 0, 0);
        }
        __syncthreads();
    }
#pragma unroll
    for (int m = 0; m < 2; ++m) {
#pragma unroll
        for (int n = 0; n < 2; ++n) {
            int col = n0 + 32 * wc + 16 * n + l15;
            float bv = bias[col];
#pragma unroll
            for (int r = 0; r < 4; ++r) {
                int row = m0 + 32 * wr + 16 * m + 4 * lhi + r;
                float v = acc[m][n][r] + bv;
                if (doRelu) v = fmaxf(v, 0.f);
                if (OUT_BF16) ((ushort_t*)C)[(size_t)row * N + col] = bf16r(v);
                else          ((float*)C)[(size_t)row * N + col] = v;
            }
        }
    }
}

// ---------------------------------------------------------------- out layer: [B,256]@[256,1] + b
__global__ void out_layer(const float* __restrict__ H2, const float* __restrict__ W,
                          const float* __restrict__ b, float* __restrict__ out) {
    int row = blockIdx.x;
    int lane = threadIdx.x;
    float4 h = ((const float4*)(H2 + row * 256))[lane];
    float4 w = ((const float4*)W)[lane];
    float acc = h.x * w.x + h.y * w.y + h.z * w.z + h.w * w.w;
    for (int off = 32; off; off >>= 1) acc += __shfl_down(acc, off, 64);
    if (lane == 0) out[row] = acc + b[0];
}

// ================================================================ launch
extern "C" void kernel_launch(void* const* d_in, const int* in_sizes, int n_in,
                              void* d_out, int out_size, void* d_ws, size_t ws_size,
                              hipStream_t stream) {
    const float* user_feat0 = (const float*)d_in[0];
    const float* user_feat1 = (const float*)d_in[1];
    const float* user_feat2 = (const float*)d_in[2];
    const float* item_feat0 = (const float*)d_in[3];
    const float* item_feat1 = (const float*)d_in[4];
    const float* item_feat2 = (const float*)d_in[5];
    const int*   user_ids   = (const int*)d_in[6];
    const int*   item_ids   = (const int*)d_in[7];
    const int*   adj_row    = (const int*)d_in[8];
    const int*   adj_col    = (const int*)d_in[9];
    const float* adj_val    = (const float*)d_in[10];
    const float* user_emb   = (const float*)d_in[11];
    const float* item_emb   = (const float*)d_in[12];
    const float* Wu0 = (const float*)d_in[13];
    const float* Wu1 = (const float*)d_in[14];
    const float* Wu2 = (const float*)d_in[15];
    const float* Wi0 = (const float*)d_in[16];
    const float* Wi1 = (const float*)d_in[17];
    const float* Wi2 = (const float*)d_in[18];
    const float* fc1_W = (const float*)d_in[19];
    const float* fc1_b = (const float*)d_in[20];
    const float* fc2_W = (const float*)d_in[21];
    const float* fc2_b = (const float*)d_in[22];
    const float* out_W = (const float*)d_in[23];
    const float* out_b = (const float*)d_in[24];
    float* out = (float*)d_out;

    // workspace carve-up (256B aligned)
    size_t off = 0;
    auto alloc = [&](size_t bytes) { size_t o = off; off += (bytes + 255) & ~(size_t)255; return o; };
    char* ws = (char*)d_ws;
    uint_t*   x0b   = (uint_t*)  (ws + alloc((size_t)NTOT * 64 * 4));
    uint_t*   x1b   = (uint_t*)  (ws + alloc((size_t)NTOT * 64 * 4));
    int*      rowp  = (int*)     (ws + alloc((size_t)(NTOT + 1) * 4));
    int*      gcnt  = (int*)     (ws + alloc((size_t)NBKT * 4));
    int*      bbase = (int*)     (ws + alloc((size_t)NBKT * 4));
    int*      bcur  = (int*)     (ws + alloc((size_t)NBKT * 4));
    int2*     pedge = (int2*)    (ws + alloc((size_t)NNZ_ * 8));
    int2*     cedge = (int2*)    (ws + alloc((size_t)NNZ_ * 8));
    ushort_t* Xh    = (ushort_t*)(ws + alloc((size_t)B_ * 1024 * 2));   // bf16 [B][1024]
    ushort_t* H1b   = (ushort_t*)(ws + alloc((size_t)B_ * 512 * 2));    // bf16 [B][512]
    float*    H2    = (float*)   (ws + alloc((size_t)B_ * 256 * 4));    // f32  [B][256]
    ushort_t* Wt1   = (ushort_t*)(ws + alloc((size_t)512 * 1024 * 2));  // bf16 [512][1024]
    ushort_t* Wt2   = (ushort_t*)(ws + alloc((size_t)256 * 512 * 2));   // bf16 [256][512]

    // 1) X0 = bf16(concat(embs)); weight transposes; bucket counters = 0
    cvt_x0<<<2048, 256, 0, stream>>>(user_emb, item_emb, x0b);
    cvt_wt<<<(1024 * 512 + 255) / 256, 256, 0, stream>>>(fc1_W, Wt1, 1024, 512);
    cvt_wt<<<(512 * 256 + 255) / 256, 256, 0, stream>>>(fc2_W, Wt2, 512, 256);
    hipMemsetAsync(gcnt, 0, (size_t)NBKT * 4, stream);

    // 2) CSR build via bucketed counting sort
    bucket_hist<<<256, 256, 0, stream>>>(adj_row, gcnt);
    bucket_scan<<<1, 256, 0, stream>>>(gcnt, bbase, bcur, rowp);
    partition_edges<<<NCH, 256, 0, stream>>>(adj_row, adj_col, adj_val, bcur, pedge);
    bucket_sort<<<NBKT, 256, 0, stream>>>(gcnt, bbase, pedge, cedge, rowp);

    // 3) propagation: Xh(sel, cols 0:256) = (x0 + x1 + x2 + x3)/4
    spmm_bf16<<<(NTOT + 3) / 4, 256, 0, stream>>>(rowp, cedge, x0b, x1b);          // x1
    gather2<<<(2 * B_ + 3) / 4, 256, 0, stream>>>(x0b, x1b, user_ids, item_ids, (uint_t*)Xh);
    spmm_bf16<<<(NTOT + 3) / 4, 256, 0, stream>>>(rowp, cedge, x1b, x0b);          // x2 (reuse x0b)
    spmm_sel<<<(2 * B_ + 3) / 4, 256, 0, stream>>>(rowp, cedge, x0b, user_ids, item_ids, (uint_t*)Xh);

    // 4) feature MLP columns (bf16 out)
    feat_gemm<64><<<B_ / 8, 128, 0, stream>>>(user_feat0, Wu0, Xh, 256);
    feat_gemm<32><<<B_ / 8, 128, 0, stream>>>(user_feat1, Wu1, Xh, 384);
    feat_gemm<16><<<B_ / 8, 128, 0, stream>>>(user_feat2, Wu2, Xh, 512);
    feat_gemm<64><<<B_ / 8, 128, 0, stream>>>(item_feat0, Wi0, Xh, 640);
    feat_gemm<32><<<B_ / 8, 128, 0, stream>>>(item_feat1, Wi1, Xh, 768);
    feat_gemm<16><<<B_ / 8, 128, 0, stream>>>(item_feat2, Wi2, Xh, 896);

    // 5) MLP tail via bf16 MFMA
    mfma_fc<1><<<dim3(512 / 64, B_ / 64), 256, 0, stream>>>(Xh, Wt1, fc1_b, H1b, B_, 512, 1024, 1);
    mfma_fc<0><<<dim3(256 / 64, B_ / 64), 256, 0, stream>>>(H1b, Wt2, fc2_b, H2, B_, 256, 512, 1);
    out_layer<<<B_, 64, 0, stream>>>(H2, out_W, out_b, out);
}

// Round 11
// 470.873 us; speedup vs baseline: 1.8270x; 1.0700x over previous
//
#include <hip/hip_runtime.h>

#define NU_   40000
#define NI_   60000
#define NTOT  100000
#define D_    128
#define NNZ_  1600000
#define B_    4096

#define BSH   7
#define NBKT  ((NTOT + 127) >> 7)            // 782 buckets of 128 rows
#define CHUNK 16384
#define NCH   ((NNZ_ + CHUNK - 1) / CHUNK)   // 98
#define BCAP  2560                            // bucket capacity (mean 2048 + 11 sigma)

typedef unsigned int uint_t;
typedef unsigned short ushort_t;
typedef __attribute__((ext_vector_type(8))) short short8v;
typedef __attribute__((ext_vector_type(4))) float float4v;

// ---- bf16 pack/unpack ----
__device__ __forceinline__ uint_t pack_bf16(float lo, float hi) {
    uint_t ul = __float_as_uint(lo);
    uint_t uh = __float_as_uint(hi);
    ul = (ul + 0x7fffu + ((ul >> 16) & 1u)) >> 16;
    uh = (uh + 0x7fffu + ((uh >> 16) & 1u)) >> 16;
    return ul | (uh << 16);
}
__device__ __forceinline__ float2 unpack_bf16(uint_t u) {
    return make_float2(__uint_as_float(u << 16), __uint_as_float(u & 0xffff0000u));
}
__device__ __forceinline__ ushort_t bf16r(float f) {
    uint_t u = __float_as_uint(f);
    return (ushort_t)((u + 0x7fffu + ((u >> 16) & 1u)) >> 16);
}

// ---------------------------------------------------------------- X0 (bf16) = concat(user_emb, item_emb)
__global__ void cvt_x0(const float* __restrict__ ue, const float* __restrict__ ie,
                       uint_t* __restrict__ x0b) {
    const int total = NTOT * 64;
    const int ucnt  = NU_ * 64;
    for (int i = blockIdx.x * blockDim.x + threadIdx.x; i < total; i += gridDim.x * blockDim.x) {
        float2 v = (i < ucnt) ? ((const float2*)ue)[i] : ((const float2*)ie)[i - ucnt];
        x0b[i] = pack_bf16(v.x, v.y);
    }
}

// ---------------------------------------------------------------- W [K][N] f32 -> Wt [N][K] bf16
__global__ void cvt_wt(const float* __restrict__ W, ushort_t* __restrict__ Wt, int K, int N) {
    int idx = blockIdx.x * blockDim.x + threadIdx.x;
    if (idx < K * N) {
        int k = idx / N, n = idx % N;
        Wt[(size_t)n * K + k] = bf16r(W[idx]);
    }
}

// ---------------------------------------------------------------- bucket histogram (LDS-staged)
__global__ __launch_bounds__(256) void bucket_hist(const int* __restrict__ row,
                                                   int* __restrict__ gcnt) {
    __shared__ int lcnt[NBKT];
    for (int i = threadIdx.x; i < NBKT; i += 256) lcnt[i] = 0;
    __syncthreads();
    for (int i = blockIdx.x * blockDim.x + threadIdx.x; i < NNZ_; i += gridDim.x * blockDim.x)
        atomicAdd(&lcnt[row[i] >> BSH], 1);
    __syncthreads();
    for (int i = threadIdx.x; i < NBKT; i += 256)
        if (lcnt[i]) atomicAdd(&gcnt[i], lcnt[i]);
}

// ---------------------------------------------------------------- bucket offsets (single block scan over 782)
__global__ __launch_bounds__(256) void bucket_scan(const int* __restrict__ gcnt,
                                                   int* __restrict__ base,
                                                   int* __restrict__ cursor,
                                                   int* __restrict__ rowp) {
    __shared__ int s[256];
    int t = threadIdx.x;
    int b0 = t * 4;
    int v[4]; int tot = 0;
#pragma unroll
    for (int i = 0; i < 4; ++i) { v[i] = (b0 + i < NBKT) ? gcnt[b0 + i] : 0; tot += v[i]; }
    s[t] = tot; __syncthreads();
    for (int off = 1; off < 256; off <<= 1) {
        int x = (t >= off) ? s[t - off] : 0; __syncthreads();
        s[t] += x; __syncthreads();
    }
    int run = s[t] - tot;
#pragma unroll
    for (int i = 0; i < 4; ++i) {
        if (b0 + i < NBKT) { base[b0 + i] = run; cursor[b0 + i] = run; }
        run += v[i];
    }
    if (t == 0) rowp[NTOT] = NNZ_;
}

// ---------------------------------------------------------------- partition: chunked count-reserve-scatter
__global__ __launch_bounds__(256) void partition_edges(const int* __restrict__ row,
                                                       const int* __restrict__ col,
                                                       const float* __restrict__ val,
                                                       int* __restrict__ cursor,
                                                       int2* __restrict__ pedge) {
    __shared__ int lcnt[NBKT];
    __shared__ int lbase[NBKT];
    int s = blockIdx.x * CHUNK;
    int e = min(s + CHUNK, NNZ_);
    for (int i = threadIdx.x; i < NBKT; i += 256) lcnt[i] = 0;
    __syncthreads();
    for (int i = s + threadIdx.x; i < e; i += 256)
        atomicAdd(&lcnt[row[i] >> BSH], 1);
    __syncthreads();
    for (int i = threadIdx.x; i < NBKT; i += 256) {
        int c = lcnt[i];
        lbase[i] = c ? atomicAdd(&cursor[i], c) : 0;
        lcnt[i] = 0;                 // reuse as running offset
    }
    __syncthreads();
    for (int i = s + threadIdx.x; i < e; i += 256) {
        int r = row[i];
        int b = r >> BSH;
        int pos = lbase[b] + atomicAdd(&lcnt[b], 1);
        pedge[pos] = make_int2(((r & 127) << 17) | col[i], __float_as_int(val[i]));
    }
}

// ---------------------------------------------------------------- per-bucket LDS counting sort -> final CSR + rowp
__global__ __launch_bounds__(256) void bucket_sort(const int* __restrict__ gcnt,
                                                   const int* __restrict__ base,
                                                   const int2* __restrict__ pedge,
                                                   int2* __restrict__ cedge,
                                                   int* __restrict__ rowp) {
    __shared__ int rcnt[128];
    __shared__ int rstart[128];
    __shared__ int roff[128];
    __shared__ int2 sedge[BCAP];
    int b = blockIdx.x;
    int t = threadIdx.x;
    int n = gcnt[b];
    if (n > BCAP) n = BCAP;
    int gb = base[b];
    if (t < 128) { rcnt[t] = 0; roff[t] = 0; }
    __syncthreads();
    for (int i = t; i < n; i += 256) atomicAdd(&rcnt[pedge[gb + i].x >> 17], 1);
    __syncthreads();
    if (t < 128) rstart[t] = rcnt[t];
    __syncthreads();
    for (int off = 1; off < 128; off <<= 1) {
        int x = (t < 128 && t >= off) ? rstart[t - off] : 0;
        __syncthreads();
        if (t < 128) rstart[t] += x;
        __syncthreads();
    }
    int ex = (t < 128) ? (rstart[t] - rcnt[t]) : 0;
    __syncthreads();
    if (t < 128) rstart[t] = ex;
    __syncthreads();
    for (int i = t; i < n; i += 256) {
        int2 ed = pedge[gb + i];
        int rl = ed.x >> 17;
        int pos = rstart[rl] + atomicAdd(&roff[rl], 1);
        sedge[pos] = make_int2(ed.x & 0x1FFFF, ed.y);
    }
    __syncthreads();
    for (int i = t; i < n; i += 256) cedge[gb + i] = sedge[i];
    if (t < 128) {
        int r = (b << BSH) + t;
        if (r < NTOT) rowp[r] = gb + rstart[t];
    }
}

// ---------------------------------------------------------------- full SpMM (bf16 in/out, fp32 acc), unroll-16 + uniform edge loads
__global__ __launch_bounds__(256) void spmm_bf16(const int* __restrict__ rowp,
                                                 const int2* __restrict__ cedge,
                                                 const uint_t* __restrict__ xb,
                                                 uint_t* __restrict__ yb) {
    int r = blockIdx.x * 4 + (threadIdx.x >> 6);
    int lane = threadIdx.x & 63;
    if (r >= NTOT) return;
    int s = __builtin_amdgcn_readfirstlane(rowp[r]);
    int e = __builtin_amdgcn_readfirstlane(rowp[r + 1]);
    float ax = 0.f, ay = 0.f;
    for (int i = s; i < e; i += 16) {
        int2 ed[16];
#pragma unroll
        for (int t = 0; t < 16; ++t) {
            int idx = i + t;
            ed[t] = cedge[idx < e ? idx : i];
            if (idx >= e) ed[t].y = 0;            // value := 0.0f for tail
        }
        uint_t g[16];
#pragma unroll
        for (int t = 0; t < 16; ++t) g[t] = xb[(size_t)(uint_t)ed[t].x * 64 + lane];
#pragma unroll
        for (int t = 0; t < 16; ++t) {
            float v = __int_as_float(ed[t].y);
            float2 xv = unpack_bf16(g[t]);
            ax = fmaf(v, xv.x, ax);
            ay = fmaf(v, xv.y, ay);
        }
    }
    yb[(size_t)r * 64 + lane] = pack_bf16(ax, ay);
}

// ---------------------------------------------------------------- Xh[:,0:256] (bf16) = x0[sel] + x1[sel]
__global__ __launch_bounds__(256) void gather2(const uint_t* __restrict__ x0b,
                                               const uint_t* __restrict__ x1b,
                                               const int* __restrict__ uids,
                                               const int* __restrict__ iids,
                                               uint_t* __restrict__ Xhu) {
    int g = blockIdx.x * 4 + (threadIdx.x >> 6);
    int lane = threadIdx.x & 63;
    if (g >= 2 * B_) return;
    int batch, seg, row;
    if (g < B_) { batch = g;      seg = 0; row = uids[g]; }
    else        { batch = g - B_; seg = 1; row = NU_ + iids[g - B_]; }
    float2 a = unpack_bf16(x0b[(size_t)row * 64 + lane]);
    float2 b = unpack_bf16(x1b[(size_t)row * 64 + lane]);
    Xhu[batch * 512 + seg * 64 + lane] = pack_bf16(a.x + b.x, a.y + b.y);
}

// ---------------------------------------------------------------- layer-3 partial SpMM on selected rows (bf16 out), unroll-16
__global__ __launch_bounds__(256) void spmm_sel(const int* __restrict__ rowp,
                                                const int2* __restrict__ cedge,
                                                const uint_t* __restrict__ x2b,
                                                const int* __restrict__ uids,
                                                const int* __restrict__ iids,
                                                uint_t* __restrict__ Xhu) {
    int g = blockIdx.x * 4 + (threadIdx.x >> 6);
    int lane = threadIdx.x & 63;
    if (g >= 2 * B_) return;
    int batch, seg, row;
    if (g < B_) { batch = g;      seg = 0; row = uids[g]; }
    else        { batch = g - B_; seg = 1; row = NU_ + iids[g - B_]; }
    float2 own = unpack_bf16(x2b[(size_t)row * 64 + lane]);
    float ax = own.x, ay = own.y;
    int s = __builtin_amdgcn_readfirstlane(rowp[row]);
    int e = __builtin_amdgcn_readfirstlane(rowp[row + 1]);
    for (int i = s; i < e; i += 16) {
        int2 ed[16];
#pragma unroll
        for (int t = 0; t < 16; ++t) {
            int idx = i + t;
            ed[t] = cedge[idx < e ? idx : i];
            if (idx >= e) ed[t].y = 0;
        }
        uint_t gv[16];
#pragma unroll
        for (int t = 0; t < 16; ++t) gv[t] = x2b[(size_t)(uint_t)ed[t].x * 64 + lane];
#pragma unroll
        for (int t = 0; t < 16; ++t) {
            float v = __int_as_float(ed[t].y);
            float2 xv = unpack_bf16(gv[t]);
            ax = fmaf(v, xv.x, ax);
            ay = fmaf(v, xv.y, ay);
        }
    }
    uint_t* p = Xhu + batch * 512 + seg * 64 + lane;
    float2 cur = unpack_bf16(*p);
    *p = pack_bf16((cur.x + ax) * 0.25f, (cur.y + ay) * 0.25f);
}

// ---------------------------------------------------------------- small feature GEMM: [B,K]@[K,128] -> Xh[:, colbase:+128] bf16
template <int K>
__global__ void feat_gemm(const float* __restrict__ A, const float* __restrict__ W,
                          ushort_t* __restrict__ Xh, int colbase) {
    __shared__ float Ws[K * 128];
    int t = threadIdx.x;
    for (int i = t; i < K * 128; i += 128) Ws[i] = W[i];
    __syncthreads();
    int row0 = blockIdx.x * 8;
    for (int r = 0; r < 8; ++r) {
        int row = row0 + r;
        const float* a = A + row * K;
        float acc = 0.f;
#pragma unroll
        for (int k = 0; k < K; ++k) acc += a[k] * Ws[k * 128 + t];
        Xh[row * 1024 + colbase + t] = bf16r(acc);
    }
}

// ---------------------------------------------------------------- bf16 MFMA GEMM: C[M,N] = act(A[M,K] @ Bt[N,K]^T + bias)
// 64x64 tile, 4 waves (2x2 of 32x32), 16x16x32 mfma, XOR-swizzled LDS.
template <int OUT_BF16>
__global__ __launch_bounds__(256) void mfma_fc(const ushort_t* __restrict__ A,   // [M][K] bf16
                                               const ushort_t* __restrict__ Bt,  // [N][K] bf16
                                               const float* __restrict__ bias,
                                               void* __restrict__ C,
                                               int M, int N, int K, int doRelu) {
    __shared__ __align__(16) ushort_t As[64 * 64];
    __shared__ __align__(16) ushort_t Bs[64 * 64];
    int t = threadIdx.x;
    int lane = t & 63, wid = t >> 6;
    int wr = wid >> 1, wc = wid & 1;
    int l15 = lane & 15, lhi = lane >> 4;
    int m0 = blockIdx.y * 64, n0 = blockIdx.x * 64;
    float4v acc[2][2] = {};
    for (int k0 = 0; k0 < K; k0 += 64) {
#pragma unroll
        for (int it = 0; it < 2; ++it) {
            int idx = t + it * 256;          // 0..511
            int r = idx >> 3, g = idx & 7;
            int gs = g ^ (r & 7);
            *(uint4*)&As[r * 64 + gs * 8] = *(const uint4*)&A[(size_t)(m0 + r) * K + k0 + g * 8];
            *(uint4*)&Bs[r * 64 + gs * 8] = *(const uint4*)&Bt[(size_t)(n0 + r) * K + k0 + g * 8];
        }
        __syncthreads();
#pragma unroll
        for (int ks = 0; ks < 2; ++ks) {
            short8v a[2], b[2];
            int g = 4 * ks + lhi;
#pragma unroll
            for (int m = 0; m < 2; ++m) {
                int ra = 32 * wr + 16 * m + l15;
                a[m] = *(short8v*)&As[ra * 64 + (g ^ (ra & 7)) * 8];
            }
#pragma unroll
            for (int n = 0; n < 2; ++n) {
                int rb = 32 * wc + 16 * n + l15;
                b[n] = *(short8v*)&Bs[rb * 64 + (g ^ (rb & 7)) * 8];
            }
#pragma unroll
            for (int m = 0; m < 2; ++m)
#pragma unroll
                for (int n = 0; n < 2; ++n)
                    acc[m][n] = __builtin_amdgcn_mfma_f32_16x16x32_bf16(a[m], b[n], acc[m][n], 0, 0, 0);
        }
        __syncthreads();
    }
#pragma unroll
    for (int m = 0; m < 2; ++m) {
#pragma unroll
        for (int n = 0; n < 2; ++n) {
            int col = n0 + 32 * wc + 16 * n + l15;
            float bv = bias[col];
#pragma unroll
            for (int r = 0; r < 4; ++r) {
                int row = m0 + 32 * wr + 16 * m + 4 * lhi + r;
                float v = acc[m][n][r] + bv;
                if (doRelu) v = fmaxf(v, 0.f);
                if (OUT_BF16) ((ushort_t*)C)[(size_t)row * N + col] = bf16r(v);
                else          ((float*)C)[(size_t)row * N + col] = v;
            }
        }
    }
}

// ---------------------------------------------------------------- out layer: [B,256]@[256,1] + b
__global__ void out_layer(const float* __restrict__ H2, const float* __restrict__ W,
                          const float* __restrict__ b, float* __restrict__ out) {
    int row = blockIdx.x;
    int lane = threadIdx.x;
    float4 h = ((const float4*)(H2 + row * 256))[lane];
    float4 w = ((const float4*)W)[lane];
    float acc = h.x * w.x + h.y * w.y + h.z * w.z + h.w * w.w;
    for (int off = 32; off; off >>= 1) acc += __shfl_down(acc, off, 64);
    if (lane == 0) out[row] = acc + b[0];
}

// ================================================================ launch
extern "C" void kernel_launch(void* const* d_in, const int* in_sizes, int n_in,
                              void* d_out, int out_size, void* d_ws, size_t ws_size,
                              hipStream_t stream) {
    const float* user_feat0 = (const float*)d_in[0];
    const float* user_feat1 = (const float*)d_in[1];
    const float* user_feat2 = (const float*)d_in[2];
    const float* item_feat0 = (const float*)d_in[3];
    const float* item_feat1 = (const float*)d_in[4];
    const float* item_feat2 = (const float*)d_in[5];
    const int*   user_ids   = (const int*)d_in[6];
    const int*   item_ids   = (const int*)d_in[7];
    const int*   adj_row    = (const int*)d_in[8];
    const int*   adj_col    = (const int*)d_in[9];
    const float* adj_val    = (const float*)d_in[10];
    const float* user_emb   = (const float*)d_in[11];
    const float* item_emb   = (const float*)d_in[12];
    const float* Wu0 = (const float*)d_in[13];
    const float* Wu1 = (const float*)d_in[14];
    const float* Wu2 = (const float*)d_in[15];
    const float* Wi0 = (const float*)d_in[16];
    const float* Wi1 = (const float*)d_in[17];
    const float* Wi2 = (const float*)d_in[18];
    const float* fc1_W = (const float*)d_in[19];
    const float* fc1_b = (const float*)d_in[20];
    const float* fc2_W = (const float*)d_in[21];
    const float* fc2_b = (const float*)d_in[22];
    const float* out_W = (const float*)d_in[23];
    const float* out_b = (const float*)d_in[24];
    float* out = (float*)d_out;

    // workspace carve-up (256B aligned)
    size_t off = 0;
    auto alloc = [&](size_t bytes) { size_t o = off; off += (bytes + 255) & ~(size_t)255; return o; };
    char* ws = (char*)d_ws;
    uint_t*   x0b   = (uint_t*)  (ws + alloc((size_t)NTOT * 64 * 4));
    uint_t*   x1b   = (uint_t*)  (ws + alloc((size_t)NTOT * 64 * 4));
    int*      rowp  = (int*)     (ws + alloc((size_t)(NTOT + 1) * 4));
    int*      gcnt  = (int*)     (ws + alloc((size_t)NBKT * 4));
    int*      bbase = (int*)     (ws + alloc((size_t)NBKT * 4));
    int*      bcur  = (int*)     (ws + alloc((size_t)NBKT * 4));
    int2*     pedge = (int2*)    (ws + alloc((size_t)NNZ_ * 8));
    int2*     cedge = (int2*)    (ws + alloc((size_t)NNZ_ * 8));
    ushort_t* Xh    = (ushort_t*)(ws + alloc((size_t)B_ * 1024 * 2));   // bf16 [B][1024]
    ushort_t* H1b   = (ushort_t*)(ws + alloc((size_t)B_ * 512 * 2));    // bf16 [B][512]
    float*    H2    = (float*)   (ws + alloc((size_t)B_ * 256 * 4));    // f32  [B][256]
    ushort_t* Wt1   = (ushort_t*)(ws + alloc((size_t)512 * 1024 * 2));  // bf16 [512][1024]
    ushort_t* Wt2   = (ushort_t*)(ws + alloc((size_t)256 * 512 * 2));   // bf16 [256][512]

    // 1) X0 = bf16(concat(embs)); weight transposes; bucket counters = 0
    cvt_x0<<<2048, 256, 0, stream>>>(user_emb, item_emb, x0b);
    cvt_wt<<<(1024 * 512 + 255) / 256, 256, 0, stream>>>(fc1_W, Wt1, 1024, 512);
    cvt_wt<<<(512 * 256 + 255) / 256, 256, 0, stream>>>(fc2_W, Wt2, 512, 256);
    hipMemsetAsync(gcnt, 0, (size_t)NBKT * 4, stream);

    // 2) CSR build via bucketed counting sort
    bucket_hist<<<256, 256, 0, stream>>>(adj_row, gcnt);
    bucket_scan<<<1, 256, 0, stream>>>(gcnt, bbase, bcur, rowp);
    partition_edges<<<NCH, 256, 0, stream>>>(adj_row, adj_col, adj_val, bcur, pedge);
    bucket_sort<<<NBKT, 256, 0, stream>>>(gcnt, bbase, pedge, cedge, rowp);

    // 3) propagation: Xh(sel, cols 0:256) = (x0 + x1 + x2 + x3)/4
    spmm_bf16<<<(NTOT + 3) / 4, 256, 0, stream>>>(rowp, cedge, x0b, x1b);          // x1
    gather2<<<(2 * B_ + 3) / 4, 256, 0, stream>>>(x0b, x1b, user_ids, item_ids, (uint_t*)Xh);
    spmm_bf16<<<(NTOT + 3) / 4, 256, 0, stream>>>(rowp, cedge, x1b, x0b);          // x2 (reuse x0b)
    spmm_sel<<<(2 * B_ + 3) / 4, 256, 0, stream>>>(rowp, cedge, x0b, user_ids, item_ids, (uint_t*)Xh);

    // 4) feature MLP columns (bf16 out)
    feat_gemm<64><<<B_ / 8, 128, 0, stream>>>(user_feat0, Wu0, Xh, 256);
    feat_gemm<32><<<B_ / 8, 128, 0, stream>>>(user_feat1, Wu1, Xh, 384);
    feat_gemm<16><<<B_ / 8, 128, 0, stream>>>(user_feat2, Wu2, Xh, 512);
    feat_gemm<64><<<B_ / 8, 128, 0, stream>>>(item_feat0, Wi0, Xh, 640);
    feat_gemm<32><<<B_ / 8, 128, 0, stream>>>(item_feat1, Wi1, Xh, 768);
    feat_gemm<16><<<B_ / 8, 128, 0, stream>>>(item_feat2, Wi2, Xh, 896);

    // 5) MLP tail via bf16 MFMA
    mfma_fc<1><<<dim3(512 / 64, B_ / 64), 256, 0, stream>>>(Xh, Wt1, fc1_b, H1b, B_, 512, 1024, 1);
    mfma_fc<0><<<dim3(256 / 64, B_ / 64), 256, 0, stream>>>(H1b, Wt2, fc2_b, H2, B_, 256, 512, 1);
    out_layer<<<B_, 64, 0, stream>>>(H2, out_W, out_b, out);
}

// Round 13
// 442.690 us; speedup vs baseline: 1.9433x; 1.0637x over previous
//
#include <hip/hip_runtime.h>

#define NU_   40000
#define NI_   60000
#define NTOT  100000
#define D_    128
#define NNZ_  1600000
#define B_    4096

#define BSH   7
#define NBKT  ((NTOT + 127) >> 7)            // 782 buckets of 128 rows
#define CHUNK 4096
#define NCH   ((NNZ_ + CHUNK - 1) / CHUNK)   // 391
#define BCAP  2560                            // bucket capacity (mean 2048 + 11 sigma)

typedef unsigned int uint_t;
typedef unsigned short ushort_t;
typedef __attribute__((ext_vector_type(8))) short short8v;
typedef __attribute__((ext_vector_type(4))) float float4v;

// ---- bf16 pack/unpack ----
__device__ __forceinline__ uint_t pack_bf16(float lo, float hi) {
    uint_t ul = __float_as_uint(lo);
    uint_t uh = __float_as_uint(hi);
    ul = (ul + 0x7fffu + ((ul >> 16) & 1u)) >> 16;
    uh = (uh + 0x7fffu + ((uh >> 16) & 1u)) >> 16;
    return ul | (uh << 16);
}
__device__ __forceinline__ float2 unpack_bf16(uint_t u) {
    return make_float2(__uint_as_float(u << 16), __uint_as_float(u & 0xffff0000u));
}
__device__ __forceinline__ ushort_t bf16r(float f) {
    uint_t u = __float_as_uint(f);
    return (ushort_t)((u + 0x7fffu + ((u >> 16) & 1u)) >> 16);
}

// ---------------------------------------------------------------- X0 (bf16) = concat(user_emb, item_emb)
__global__ void cvt_x0(const float* __restrict__ ue, const float* __restrict__ ie,
                       uint_t* __restrict__ x0b) {
    const int total = NTOT * 64;
    const int ucnt  = NU_ * 64;
    for (int i = blockIdx.x * blockDim.x + threadIdx.x; i < total; i += gridDim.x * blockDim.x) {
        float2 v = (i < ucnt) ? ((const float2*)ue)[i] : ((const float2*)ie)[i - ucnt];
        x0b[i] = pack_bf16(v.x, v.y);
    }
}

// ---------------------------------------------------------------- W [K][N] f32 -> Wt [N][K] bf16
__global__ void cvt_wt(const float* __restrict__ W, ushort_t* __restrict__ Wt, int K, int N) {
    int idx = blockIdx.x * blockDim.x + threadIdx.x;
    if (idx < K * N) {
        int k = idx / N, n = idx % N;
        Wt[(size_t)n * K + k] = bf16r(W[idx]);
    }
}

// ---------------------------------------------------------------- bucket histogram (LDS-staged)
__global__ __launch_bounds__(256) void bucket_hist(const int* __restrict__ row,
                                                   int* __restrict__ gcnt) {
    __shared__ int lcnt[NBKT];
    for (int i = threadIdx.x; i < NBKT; i += 256) lcnt[i] = 0;
    __syncthreads();
    for (int i = blockIdx.x * blockDim.x + threadIdx.x; i < NNZ_; i += gridDim.x * blockDim.x)
        atomicAdd(&lcnt[row[i] >> BSH], 1);
    __syncthreads();
    for (int i = threadIdx.x; i < NBKT; i += 256)
        if (lcnt[i]) atomicAdd(&gcnt[i], lcnt[i]);
}

// ---------------------------------------------------------------- bucket offsets (single block scan over 782)
__global__ __launch_bounds__(256) void bucket_scan(const int* __restrict__ gcnt,
                                                   int* __restrict__ base,
                                                   int* __restrict__ cursor,
                                                   int* __restrict__ rowp) {
    __shared__ int s[256];
    int t = threadIdx.x;
    int b0 = t * 4;
    int v[4]; int tot = 0;
#pragma unroll
    for (int i = 0; i < 4; ++i) { v[i] = (b0 + i < NBKT) ? gcnt[b0 + i] : 0; tot += v[i]; }
    s[t] = tot; __syncthreads();
    for (int off = 1; off < 256; off <<= 1) {
        int x = (t >= off) ? s[t - off] : 0; __syncthreads();
        s[t] += x; __syncthreads();
    }
    int run = s[t] - tot;
#pragma unroll
    for (int i = 0; i < 4; ++i) {
        if (b0 + i < NBKT) { base[b0 + i] = run; cursor[b0 + i] = run; }
        run += v[i];
    }
    if (t == 0) rowp[NTOT] = NNZ_;
}

// ---------------------------------------------------------------- partition: chunked count-reserve-scatter
// CHUNK=4096 -> 391 blocks (occupancy fix; round-11 counters showed 3.7% occupancy at 98 blocks)
__global__ __launch_bounds__(256) void partition_edges(const int* __restrict__ row,
                                                       const int* __restrict__ col,
                                                       const float* __restrict__ val,
                                                       int* __restrict__ cursor,
                                                       int2* __restrict__ pedge) {
    __shared__ int lcnt[NBKT];
    __shared__ int lbase[NBKT];
    int s = blockIdx.x * CHUNK;
    int e = min(s + CHUNK, NNZ_);
    for (int i = threadIdx.x; i < NBKT; i += 256) lcnt[i] = 0;
    __syncthreads();
    for (int i = s + threadIdx.x; i < e; i += 256)
        atomicAdd(&lcnt[row[i] >> BSH], 1);
    __syncthreads();
    for (int i = threadIdx.x; i < NBKT; i += 256) {
        int c = lcnt[i];
        lbase[i] = c ? atomicAdd(&cursor[i], c) : 0;
        lcnt[i] = 0;                 // reuse as running offset
    }
    __syncthreads();
    for (int i = s + threadIdx.x; i < e; i += 256) {
        int r = row[i];
        int b = r >> BSH;
        int pos = lbase[b] + atomicAdd(&lcnt[b], 1);
        pedge[pos] = make_int2(((r & 127) << 17) | col[i], __float_as_int(val[i]));
    }
}

// ---------------------------------------------------------------- per-bucket LDS counting sort -> final CSR + rowp
__global__ __launch_bounds__(256) void bucket_sort(const int* __restrict__ gcnt,
                                                   const int* __restrict__ base,
                                                   const int2* __restrict__ pedge,
                                                   int2* __restrict__ cedge,
                                                   int* __restrict__ rowp) {
    __shared__ int rcnt[128];
    __shared__ int rstart[128];
    __shared__ int roff[128];
    __shared__ int2 sedge[BCAP];
    int b = blockIdx.x;
    int t = threadIdx.x;
    int n = gcnt[b];
    if (n > BCAP) n = BCAP;
    int gb = base[b];
    if (t < 128) { rcnt[t] = 0; roff[t] = 0; }
    __syncthreads();
    for (int i = t; i < n; i += 256) atomicAdd(&rcnt[pedge[gb + i].x >> 17], 1);
    __syncthreads();
    if (t < 128) rstart[t] = rcnt[t];
    __syncthreads();
    for (int off = 1; off < 128; off <<= 1) {
        int x = (t < 128 && t >= off) ? rstart[t - off] : 0;
        __syncthreads();
        if (t < 128) rstart[t] += x;
        __syncthreads();
    }
    int ex = (t < 128) ? (rstart[t] - rcnt[t]) : 0;
    __syncthreads();
    if (t < 128) rstart[t] = ex;
    __syncthreads();
    for (int i = t; i < n; i += 256) {
        int2 ed = pedge[gb + i];
        int rl = ed.x >> 17;
        int pos = rstart[rl] + atomicAdd(&roff[rl], 1);
        sedge[pos] = make_int2(ed.x & 0x1FFFF, ed.y);
    }
    __syncthreads();
    for (int i = t; i < n; i += 256) cedge[gb + i] = sedge[i];
    if (t < 128) {
        int r = (b << BSH) + t;
        if (r < NTOT) rowp[r] = gb + rstart[t];
    }
}

// ---------------------------------------------------------------- full SpMM (bf16 in/out, fp32 acc), unroll-16 + uniform edge loads
__global__ __launch_bounds__(256) void spmm_bf16(const int* __restrict__ rowp,
                                                 const int2* __restrict__ cedge,
                                                 const uint_t* __restrict__ xb,
                                                 uint_t* __restrict__ yb) {
    int r = blockIdx.x * 4 + (threadIdx.x >> 6);
    int lane = threadIdx.x & 63;
    if (r >= NTOT) return;
    int s = __builtin_amdgcn_readfirstlane(rowp[r]);
    int e = __builtin_amdgcn_readfirstlane(rowp[r + 1]);
    float ax = 0.f, ay = 0.f;
    for (int i = s; i < e; i += 16) {
        int2 ed[16];
#pragma unroll
        for (int t = 0; t < 16; ++t) {
            int idx = i + t;
            ed[t] = cedge[idx < e ? idx : i];
            if (idx >= e) ed[t].y = 0;            // value := 0.0f for tail
        }
        uint_t g[16];
#pragma unroll
        for (int t = 0; t < 16; ++t) g[t] = xb[(size_t)(uint_t)ed[t].x * 64 + lane];
#pragma unroll
        for (int t = 0; t < 16; ++t) {
            float v = __int_as_float(ed[t].y);
            float2 xv = unpack_bf16(g[t]);
            ax = fmaf(v, xv.x, ax);
            ay = fmaf(v, xv.y, ay);
        }
    }
    yb[(size_t)r * 64 + lane] = pack_bf16(ax, ay);
}

// ---------------------------------------------------------------- Xh[:,0:256] (bf16) = x0[sel] + x1[sel]
__global__ __launch_bounds__(256) void gather2(const uint_t* __restrict__ x0b,
                                               const uint_t* __restrict__ x1b,
                                               const int* __restrict__ uids,
                                               const int* __restrict__ iids,
                                               uint_t* __restrict__ Xhu) {
    int g = blockIdx.x * 4 + (threadIdx.x >> 6);
    int lane = threadIdx.x & 63;
    if (g >= 2 * B_) return;
    int batch, seg, row;
    if (g < B_) { batch = g;      seg = 0; row = uids[g]; }
    else        { batch = g - B_; seg = 1; row = NU_ + iids[g - B_]; }
    float2 a = unpack_bf16(x0b[(size_t)row * 64 + lane]);
    float2 b = unpack_bf16(x1b[(size_t)row * 64 + lane]);
    Xhu[batch * 512 + seg * 64 + lane] = pack_bf16(a.x + b.x, a.y + b.y);
}

// ---------------------------------------------------------------- layer-3 partial SpMM on selected rows (bf16 out), unroll-16
__global__ __launch_bounds__(256) void spmm_sel(const int* __restrict__ rowp,
                                                const int2* __restrict__ cedge,
                                                const uint_t* __restrict__ x2b,
                                                const int* __restrict__ uids,
                                                const int* __restrict__ iids,
                                                uint_t* __restrict__ Xhu) {
    int g = blockIdx.x * 4 + (threadIdx.x >> 6);
    int lane = threadIdx.x & 63;
    if (g >= 2 * B_) return;
    int batch, seg, row;
    if (g < B_) { batch = g;      seg = 0; row = uids[g]; }
    else        { batch = g - B_; seg = 1; row = NU_ + iids[g - B_]; }
    float2 own = unpack_bf16(x2b[(size_t)row * 64 + lane]);
    float ax = own.x, ay = own.y;
    int s = __builtin_amdgcn_readfirstlane(rowp[row]);
    int e = __builtin_amdgcn_readfirstlane(rowp[row + 1]);
    for (int i = s; i < e; i += 16) {
        int2 ed[16];
#pragma unroll
        for (int t = 0; t < 16; ++t) {
            int idx = i + t;
            ed[t] = cedge[idx < e ? idx : i];
            if (idx >= e) ed[t].y = 0;
        }
        uint_t gv[16];
#pragma unroll
        for (int t = 0; t < 16; ++t) gv[t] = x2b[(size_t)(uint_t)ed[t].x * 64 + lane];
#pragma unroll
        for (int t = 0; t < 16; ++t) {
            float v = __int_as_float(ed[t].y);
            float2 xv = unpack_bf16(gv[t]);
            ax = fmaf(v, xv.x, ax);
            ay = fmaf(v, xv.y, ay);
        }
    }
    uint_t* p = Xhu + batch * 512 + seg * 64 + lane;
    float2 cur = unpack_bf16(*p);
    *p = pack_bf16((cur.x + ax) * 0.25f, (cur.y + ay) * 0.25f);
}

// ---------------------------------------------------------------- small feature GEMM: [B,K]@[K,128] -> Xh[:, colbase:+128] bf16
template <int K>
__global__ void feat_gemm(const float* __restrict__ A, const float* __restrict__ W,
                          ushort_t* __restrict__ Xh, int colbase) {
    __shared__ float Ws[K * 128];
    int t = threadIdx.x;
    for (int i = t; i < K * 128; i += 128) Ws[i] = W[i];
    __syncthreads();
    int row0 = blockIdx.x * 8;
    for (int r = 0; r < 8; ++r) {
        int row = row0 + r;
        const float* a = A + row * K;
        float acc = 0.f;
#pragma unroll
        for (int k = 0; k < K; ++k) acc += a[k] * Ws[k * 128 + t];
        Xh[row * 1024 + colbase + t] = bf16r(acc);
    }
}

// ---------------------------------------------------------------- bf16 MFMA GEMM: C[M,N] = act(A[M,K] @ Bt[N,K]^T + bias)
// 64x64 tile, 4 waves (2x2 of 32x32), 16x16x32 mfma, XOR-swizzled LDS.
template <int OUT_BF16>
__global__ __launch_bounds__(256) void mfma_fc(const ushort_t* __restrict__ A,   // [M][K] bf16
                                               const ushort_t* __restrict__ Bt,  // [N][K] bf16
                                               const float* __restrict__ bias,
                                               void* __restrict__ C,
                                               int M, int N, int K, int doRelu) {
    __shared__ __align__(16) ushort_t As[64 * 64];
    __shared__ __align__(16) ushort_t Bs[64 * 64];
    int t = threadIdx.x;
    int lane = t & 63, wid = t >> 6;
    int wr = wid >> 1, wc = wid & 1;
    int l15 = lane & 15, lhi = lane >> 4;
    int m0 = blockIdx.y * 64, n0 = blockIdx.x * 64;
    float4v acc[2][2] = {};
    for (int k0 = 0; k0 < K; k0 += 64) {
#pragma unroll
        for (int it = 0; it < 2; ++it) {
            int idx = t + it * 256;          // 0..511
            int r = idx >> 3, g = idx & 7;
            int gs = g ^ (r & 7);
            *(uint4*)&As[r * 64 + gs * 8] = *(const uint4*)&A[(size_t)(m0 + r) * K + k0 + g * 8];
            *(uint4*)&Bs[r * 64 + gs * 8] = *(const uint4*)&Bt[(size_t)(n0 + r) * K + k0 + g * 8];
        }
        __syncthreads();
#pragma unroll
        for (int ks = 0; ks < 2; ++ks) {
            short8v a[2], b[2];
            int g = 4 * ks + lhi;
#pragma unroll
            for (int m = 0; m < 2; ++m) {
                int ra = 32 * wr + 16 * m + l15;
                a[m] = *(short8v*)&As[ra * 64 + (g ^ (ra & 7)) * 8];
            }
#pragma unroll
            for (int n = 0; n < 2; ++n) {
                int rb = 32 * wc + 16 * n + l15;
                b[n] = *(short8v*)&Bs[rb * 64 + (g ^ (rb & 7)) * 8];
            }
#pragma unroll
            for (int m = 0; m < 2; ++m)
#pragma unroll
                for (int n = 0; n < 2; ++n)
                    acc[m][n] = __builtin_amdgcn_mfma_f32_16x16x32_bf16(a[m], b[n], acc[m][n], 0, 0, 0);
        }
        __syncthreads();
    }
#pragma unroll
    for (int m = 0; m < 2; ++m) {
#pragma unroll
        for (int n = 0; n < 2; ++n) {
            int col = n0 + 32 * wc + 16 * n + l15;
            float bv = bias[col];
#pragma unroll
            for (int r = 0; r < 4; ++r) {
                int row = m0 + 32 * wr + 16 * m + 4 * lhi + r;
                float v = acc[m][n][r] + bv;
                if (doRelu) v = fmaxf(v, 0.f);
                if (OUT_BF16) ((ushort_t*)C)[(size_t)row * N + col] = bf16r(v);
                else          ((float*)C)[(size_t)row * N + col] = v;
            }
        }
    }
}

// ---------------------------------------------------------------- out layer: [B,256]@[256,1] + b
__global__ void out_layer(const float* __restrict__ H2, const float* __restrict__ W,
                          const float* __restrict__ b, float* __restrict__ out) {
    int row = blockIdx.x;
    int lane = threadIdx.x;
    float4 h = ((const float4*)(H2 + row * 256))[lane];
    float4 w = ((const float4*)W)[lane];
    float acc = h.x * w.x + h.y * w.y + h.z * w.z + h.w * w.w;
    for (int off = 32; off; off >>= 1) acc += __shfl_down(acc, off, 64);
    if (lane == 0) out[row] = acc + b[0];
}

// ================================================================ launch
extern "C" void kernel_launch(void* const* d_in, const int* in_sizes, int n_in,
                              void* d_out, int out_size, void* d_ws, size_t ws_size,
                              hipStream_t stream) {
    const float* user_feat0 = (const float*)d_in[0];
    const float* user_feat1 = (const float*)d_in[1];
    const float* user_feat2 = (const float*)d_in[2];
    const float* item_feat0 = (const float*)d_in[3];
    const float* item_feat1 = (const float*)d_in[4];
    const float* item_feat2 = (const float*)d_in[5];
    const int*   user_ids   = (const int*)d_in[6];
    const int*   item_ids   = (const int*)d_in[7];
    const int*   adj_row    = (const int*)d_in[8];
    const int*   adj_col    = (const int*)d_in[9];
    const float* adj_val    = (const float*)d_in[10];
    const float* user_emb   = (const float*)d_in[11];
    const float* item_emb   = (const float*)d_in[12];
    const float* Wu0 = (const float*)d_in[13];
    const float* Wu1 = (const float*)d_in[14];
    const float* Wu2 = (const float*)d_in[15];
    const float* Wi0 = (const float*)d_in[16];
    const float* Wi1 = (const float*)d_in[17];
    const float* Wi2 = (const float*)d_in[18];
    const float* fc1_W = (const float*)d_in[19];
    const float* fc1_b = (const float*)d_in[20];
    const float* fc2_W = (const float*)d_in[21];
    const float* fc2_b = (const float*)d_in[22];
    const float* out_W = (const float*)d_in[23];
    const float* out_b = (const float*)d_in[24];
    float* out = (float*)d_out;

    // workspace carve-up (256B aligned)
    size_t off = 0;
    auto alloc = [&](size_t bytes) { size_t o = off; off += (bytes + 255) & ~(size_t)255; return o; };
    char* ws = (char*)d_ws;
    uint_t*   x0b   = (uint_t*)  (ws + alloc((size_t)NTOT * 64 * 4));
    uint_t*   x1b   = (uint_t*)  (ws + alloc((size_t)NTOT * 64 * 4));
    int*      rowp  = (int*)     (ws + alloc((size_t)(NTOT + 1) * 4));
    int*      gcnt  = (int*)     (ws + alloc((size_t)NBKT * 4));
    int*      bbase = (int*)     (ws + alloc((size_t)NBKT * 4));
    int*      bcur  = (int*)     (ws + alloc((size_t)NBKT * 4));
    int2*     pedge = (int2*)    (ws + alloc((size_t)NNZ_ * 8));
    int2*     cedge = (int2*)    (ws + alloc((size_t)NNZ_ * 8));
    ushort_t* Xh    = (ushort_t*)(ws + alloc((size_t)B_ * 1024 * 2));   // bf16 [B][1024]
    ushort_t* H1b   = (ushort_t*)(ws + alloc((size_t)B_ * 512 * 2));    // bf16 [B][512]
    float*    H2    = (float*)   (ws + alloc((size_t)B_ * 256 * 4));    // f32  [B][256]
    ushort_t* Wt1   = (ushort_t*)(ws + alloc((size_t)512 * 1024 * 2));  // bf16 [512][1024]
    ushort_t* Wt2   = (ushort_t*)(ws + alloc((size_t)256 * 512 * 2));   // bf16 [256][512]

    // 1) X0 = bf16(concat(embs)); weight transposes; bucket counters = 0
    cvt_x0<<<2048, 256, 0, stream>>>(user_emb, item_emb, x0b);
    cvt_wt<<<(1024 * 512 + 255) / 256, 256, 0, stream>>>(fc1_W, Wt1, 1024, 512);
    cvt_wt<<<(512 * 256 + 255) / 256, 256, 0, stream>>>(fc2_W, Wt2, 512, 256);
    hipMemsetAsync(gcnt, 0, (size_t)NBKT * 4, stream);

    // 2) CSR build via bucketed counting sort
    bucket_hist<<<256, 256, 0, stream>>>(adj_row, gcnt);
    bucket_scan<<<1, 256, 0, stream>>>(gcnt, bbase, bcur, rowp);
    partition_edges<<<NCH, 256, 0, stream>>>(adj_row, adj_col, adj_val, bcur, pedge);
    bucket_sort<<<NBKT, 256, 0, stream>>>(gcnt, bbase, pedge, cedge, rowp);

    // 3) propagation: Xh(sel, cols 0:256) = (x0 + x1 + x2 + x3)/4
    spmm_bf16<<<(NTOT + 3) / 4, 256, 0, stream>>>(rowp, cedge, x0b, x1b);          // x1
    gather2<<<(2 * B_ + 3) / 4, 256, 0, stream>>>(x0b, x1b, user_ids, item_ids, (uint_t*)Xh);
    spmm_bf16<<<(NTOT + 3) / 4, 256, 0, stream>>>(rowp, cedge, x1b, x0b);          // x2 (reuse x0b)
    spmm_sel<<<(2 * B_ + 3) / 4, 256, 0, stream>>>(rowp, cedge, x0b, user_ids, item_ids, (uint_t*)Xh);

    // 4) feature MLP columns (bf16 out)
    feat_gemm<64><<<B_ / 8, 128, 0, stream>>>(user_feat0, Wu0, Xh, 256);
    feat_gemm<32><<<B_ / 8, 128, 0, stream>>>(user_feat1, Wu1, Xh, 384);
    feat_gemm<16><<<B_ / 8, 128, 0, stream>>>(user_feat2, Wu2, Xh, 512);
    feat_gemm<64><<<B_ / 8, 128, 0, stream>>>(item_feat0, Wi0, Xh, 640);
    feat_gemm<32><<<B_ / 8, 128, 0, stream>>>(item_feat1, Wi1, Xh, 768);
    feat_gemm<16><<<B_ / 8, 128, 0, stream>>>(item_feat2, Wi2, Xh, 896);

    // 5) MLP tail via bf16 MFMA
    mfma_fc<1><<<dim3(512 / 64, B_ / 64), 256, 0, stream>>>(Xh, Wt1, fc1_b, H1b, B_, 512, 1024, 1);
    mfma_fc<0><<<dim3(256 / 64, B_ / 64), 256, 0, stream>>>(H1b, Wt2, fc2_b, H2, B_, 256, 512, 1);
    out_layer<<<B_, 64, 0, stream>>>(H2, out_W, out_b, out);
}